// Round 22
// baseline (235.021 us; speedup 1.0000x reference)
//
#include <hip/hip_runtime.h>
#include <hip/hip_bf16.h>

#define N_ATOM 8192
#define N_PROT 16384
#define N_FRAG 1024
#define KNN    32
#define OUTC   649   // 128 + 192 + 128 + 192 + 9

typedef __attribute__((ext_vector_type(8))) short bf16x8;
typedef __attribute__((ext_vector_type(4))) float f32x4;

__device__ __forceinline__ float silu_f(float x){ return x / (1.f + __expf(-x)); }
__device__ __forceinline__ unsigned long long ullmin2(unsigned long long a, unsigned long long b){ return a < b ? a : b; }

__device__ __forceinline__ short f2bf(float x){
    __hip_bfloat16 h = __float2bfloat16(x);
    return *reinterpret_cast<short*>(&h);
}
// packed pair: 2 f32 -> 2 bf16 in one u32
__device__ __forceinline__ unsigned f2bf2(float lo, float hi){
    __hip_bfloat162 h2;
    h2.x = __float2bfloat16(lo);
    h2.y = __float2bfloat16(hi);
    return *reinterpret_cast<unsigned*>(&h2);
}
__device__ __forceinline__ float bf2f(short s){
    return __uint_as_float(((unsigned)(unsigned short)s) << 16);
}

// ================================================================ prep device parts (all elementwise, no LDS)
// pack id ranges (total 50688)
__device__ void dev_pack(int id,
                         const float* __restrict__ W1, const float* __restrict__ W2,
                         const float* __restrict__ Ws, const float* __restrict__ Wv,
                         const float* __restrict__ W1a, const float* __restrict__ W2a,
                         const float* __restrict__ Wsa, const float* __restrict__ Wva,
                         const float* __restrict__ Wos, const float* __restrict__ Wov,
                         short* __restrict__ W1p, short* __restrict__ W2p,
                         short* __restrict__ Wsp, short* __restrict__ Wvp,
                         short* __restrict__ W1cp,
                         short* __restrict__ W1ap, short* __restrict__ W2ap,
                         short* __restrict__ Wsap, short* __restrict__ Wvap,
                         short* __restrict__ Wosp, short* __restrict__ Wovp){
    if (id < 5120){
        int kt = id/1024, rem = id%1024, nt = rem/64, l = rem%64;
#pragma unroll
        for (int jj = 0; jj < 8; ++jj){
            int k = kt*32 + ((l>>4)<<3) + jj, n = nt*16 + (l&15);
            W1p[(size_t)id*8 + jj] = (k < 144) ? f2bf(W1[(size_t)k*256 + n]) : (short)0;
        }
    } else if (id < 13312){
        int id2 = id - 5120;
        int kt = id2/1024, rem = id2%1024, nt = rem/64, l = rem%64;
#pragma unroll
        for (int jj = 0; jj < 8; ++jj){
            int k = kt*32 + ((l>>4)<<3) + jj, n = nt*16 + (l&15);
            W2p[(size_t)id2*8 + jj] = f2bf(W2[(size_t)k*256 + n]);
        }
    } else if (id < 15360){
        int id2 = id - 13312;
        int kt = id2/512, rem = id2%512, nt = rem/64, l = rem%64;
#pragma unroll
        for (int jj = 0; jj < 8; ++jj){
            int k = kt*32 + ((l>>4)<<3) + jj, n = nt*16 + (l&15);
            Wsp[(size_t)id2*8 + jj] = f2bf(Ws[(size_t)k*128 + n]);
        }
    } else if (id < 15872){
        int id2 = id - 15360;
        int kt = id2/256, rem = id2%256, nt = rem/64, l = rem%64;
#pragma unroll
        for (int jj = 0; jj < 8; ++jj){
            int k = kt*32 + ((l>>4)<<3) + jj, n = nt*16 + (l&15);
            Wvp[(size_t)id2*8 + jj] = f2bf(Wv[(size_t)k*64 + n]);
        }
    } else if (id < 24064){
        int id2 = id - 15872;
        int kt = id2/1024, rem = id2%1024, nt = rem/64, l = rem%64;
#pragma unroll
        for (int jj = 0; jj < 8; ++jj){
            int k = kt*32 + ((l>>4)<<3) + jj, n = nt*16 + (l&15);
            W1cp[(size_t)id2*8 + jj] = f2bf(W1[(size_t)(144 + k)*256 + n]);
        }
    } else if (id < 37376){
        int id2 = id - 24064;
        int kt = id2/1024, rem = id2%1024, nt = rem/64, l = rem%64;
#pragma unroll
        for (int jj = 0; jj < 8; ++jj){
            int k = kt*32 + ((l>>4)<<3) + jj, n = nt*16 + (l&15);
            W1ap[(size_t)id2*8 + jj] = (k < 400) ? f2bf(W1a[(size_t)k*256 + n]) : (short)0;
        }
    } else if (id < 45568){
        int id2 = id - 37376;
        int kt = id2/1024, rem = id2%1024, nt = rem/64, l = rem%64;
#pragma unroll
        for (int jj = 0; jj < 8; ++jj){
            int k = kt*32 + ((l>>4)<<3) + jj, n = nt*16 + (l&15);
            W2ap[(size_t)id2*8 + jj] = f2bf(W2a[(size_t)k*256 + n]);
        }
    } else if (id < 47616){
        int id2 = id - 45568;
        int kt = id2/512, rem = id2%512, nt = rem/64, l = rem%64;
#pragma unroll
        for (int jj = 0; jj < 8; ++jj){
            int k = kt*32 + ((l>>4)<<3) + jj, n = nt*16 + (l&15);
            Wsap[(size_t)id2*8 + jj] = f2bf(Wsa[(size_t)k*128 + n]);
        }
    } else if (id < 48128){
        int id2 = id - 47616;
        int kt = id2/256, rem = id2%256, nt = rem/64, l = rem%64;
#pragma unroll
        for (int jj = 0; jj < 8; ++jj){
            int k = kt*32 + ((l>>4)<<3) + jj, n = nt*16 + (l&15);
            Wvap[(size_t)id2*8 + jj] = f2bf(Wva[(size_t)k*64 + n]);
        }
    } else if (id < 50176){
        int id2 = id - 48128;
        int kt = id2/512, rem = id2%512, nt = rem/64, l = rem%64;
#pragma unroll
        for (int jj = 0; jj < 8; ++jj){
            int k = kt*32 + ((l>>4)<<3) + jj, n = nt*16 + (l&15);
            Wosp[(size_t)id2*8 + jj] = f2bf(Wos[(size_t)k*128 + n]);
        }
    } else if (id < 50688){
        int id2 = id - 50176;
        int kt = id2/256, rem = id2%256, nt = rem/64, l = rem%64;
#pragma unroll
        for (int jj = 0; jj < 8; ++jj){
            int k = kt*32 + ((l>>4)<<3) + jj, n = nt*16 + (l&15);
            Wovp[(size_t)id2*8 + jj] = f2bf(Wov[(size_t)k*64 + n]);
        }
    }
}

// ---------------------------------------------------------------- fused prep
#define PREP_B0 198                   // pack: 50688 ids
#define PREP_B1 (PREP_B0 + 2560)     // cvt: N_PROT*(16+24)
#define PREP_B2 (PREP_B1 + 1)        // ranges
#define PREP_B3 (PREP_B2 + 64)       // hfsB: 16384 ids
#define PREP_B4 (PREP_B3 + 512)      // tembB: 131072 ids
#define PREP_B5 (PREP_B4 + 32)       // fragsum: 8192 threads
#define PREP_NB (PREP_B5 + 64)       // ppos4: 16384 ids
__global__ __launch_bounds__(256) void k_prep(
    const float* __restrict__ W1, const float* __restrict__ W2,
    const float* __restrict__ Ws, const float* __restrict__ Wv,
    const float* __restrict__ W1a, const float* __restrict__ W2a,
    const float* __restrict__ Wsa, const float* __restrict__ Wva,
    const float* __restrict__ Wos, const float* __restrict__ Wov,
    const float* __restrict__ hps, const float* __restrict__ hpv,
    const float* __restrict__ hfsF, const float* __restrict__ tembF,
    const float* __restrict__ apos, const float* __restrict__ lpos,
    const float* __restrict__ ppos,
    const int* __restrict__ fid, const int* __restrict__ pbatch,
    short* __restrict__ W1p, short* __restrict__ W2p,
    short* __restrict__ Wsp, short* __restrict__ Wvp,
    short* __restrict__ W1cp,
    short* __restrict__ W1ap, short* __restrict__ W2ap,
    short* __restrict__ Wsap, short* __restrict__ Wvap,
    short* __restrict__ Wosp, short* __restrict__ Wovp,
    short* __restrict__ hpsB, short* __restrict__ hpvT,
    short* __restrict__ hfsB, short* __restrict__ tembB,
    float* __restrict__ ppos4,
    int* __restrict__ pstart,
    float* __restrict__ cnt, float* __restrict__ tsum, float* __restrict__ isum)
{
    const int b = blockIdx.x, t = threadIdx.x;
    if (b < PREP_B0){
        dev_pack(b*256 + t, W1, W2, Ws, Wv, W1a, W2a, Wsa, Wva, Wos, Wov,
                 W1p, W2p, Wsp, Wvp, W1cp, W1ap, W2ap, Wsap, Wvap, Wosp, Wovp);
    } else if (b < PREP_B1){
        int id = (b - PREP_B0)*256 + t;
        if (id < N_PROT*16){
            const float* s = hps + (size_t)id*8;
            float4 x0 = *(const float4*)(s);
            float4 x1 = *(const float4*)(s+4);
            unsigned* d = (unsigned*)(hpsB + (size_t)id*8);
            d[0] = f2bf2(x0.x, x0.y); d[1] = f2bf2(x0.z, x0.w);
            d[2] = f2bf2(x1.x, x1.y); d[3] = f2bf2(x1.z, x1.w);
        } else {
            int id2 = id - N_PROT*16;
            int j = id2 / 24, r = id2 % 24;
            short tmp[8];
#pragma unroll
            for (int u = 0; u < 8; ++u){
                int o = r*8 + u, c = o >> 6, v = o & 63;
                tmp[u] = f2bf(hpv[(size_t)j*192 + v*3 + c]);
            }
            *(bf16x8*)(hpvT + (size_t)j*192 + r*8) = *(bf16x8*)tmp;
        }
    } else if (b < PREP_B2){
        if (t <= 8){
            int lo = 0, hi = N_PROT;
            while (lo < hi){ int mid = (lo + hi) >> 1; if (pbatch[mid] < t) lo = mid + 1; else hi = mid; }
            pstart[t] = lo;
        }
    } else if (b < PREP_B3){
        int id = (b - PREP_B2)*256 + t;
        const float* s = hfsF + (size_t)id*8;
        float4 x0 = *(const float4*)(s);
        float4 x1 = *(const float4*)(s+4);
        unsigned* d = (unsigned*)(hfsB + (size_t)id*8);
        d[0] = f2bf2(x0.x, x0.y); d[1] = f2bf2(x0.z, x0.w);
        d[2] = f2bf2(x1.x, x1.y); d[3] = f2bf2(x1.z, x1.w);
    } else if (b < PREP_B4){
        int id = (b - PREP_B3)*256 + t;
        const float* s = tembF + (size_t)id*8;
        float4 x0 = *(const float4*)(s);
        float4 x1 = *(const float4*)(s+4);
        unsigned* d = (unsigned*)(tembB + (size_t)id*8);
        d[0] = f2bf2(x0.x, x0.y); d[1] = f2bf2(x0.z, x0.w);
        d[2] = f2bf2(x1.x, x1.y); d[3] = f2bf2(x1.z, x1.w);
    } else if (b < PREP_B5){
        int a = (b - PREP_B4)*256 + t;
        if (a < N_ATOM){
            int f = fid[a];
            atomicAdd(&cnt[f], 1.f);
            atomicAdd(&tsum[f*3+0], apos[a*3+0]);
            atomicAdd(&tsum[f*3+1], apos[a*3+1]);
            atomicAdd(&tsum[f*3+2], apos[a*3+2]);
            float x = lpos[a*3+0], y = lpos[a*3+1], z = lpos[a*3+2];
            float r2 = x*x + y*y + z*z;
            atomicAdd(&isum[f*9+0], r2 - x*x);
            atomicAdd(&isum[f*9+1], -(x*y));
            atomicAdd(&isum[f*9+2], -(x*z));
            atomicAdd(&isum[f*9+3], -(y*x));
            atomicAdd(&isum[f*9+4], r2 - y*y);
            atomicAdd(&isum[f*9+5], -(y*z));
            atomicAdd(&isum[f*9+6], -(z*x));
            atomicAdd(&isum[f*9+7], -(z*y));
            atomicAdd(&isum[f*9+8], r2 - z*z);
        }
    } else {
        int j = (b - PREP_B5)*256 + t;
        if (j < N_PROT){
            float px = ppos[j*3+0], py = ppos[j*3+1], pz = ppos[j*3+2];
            float p2 = px*px + py*py + pz*pz;
            *(float4*)(ppos4 + (size_t)j*4) = make_float4(px, py, pz, p2);
        }
    }
}

// ---------------------------------------------------------------- KNN: single-level linear-d2 radix select (exact top-32)
__global__ __launch_bounds__(256) void k_knn(const float* __restrict__ apos,
                                             const float* __restrict__ ppos4,
                                             const int* __restrict__ abatch,
                                             const int* __restrict__ pstart,
                                             int* __restrict__ src_out){
    __shared__ int h1[256];
    __shared__ int s_info[4];
    __shared__ int s_nsel;
    __shared__ int s_nbound;
    __shared__ unsigned long long s_bound[512];

    const int i = blockIdx.x, t = threadIdx.x;
    const int lane = t & 63;
    const int b = abatch[i];
    const int p0 = pstart[b], p1 = pstart[b+1];
    const float ax = apos[i*3+0], ay = apos[i*3+1], az = apos[i*3+2];
    const float a2 = ax*ax + ay*ay + az*az;
    const float BINSCALE = 256.0f / 9.0f;
    const float4* pp4 = (const float4*)ppos4;

    unsigned kb[12];
    int jj[12];
    int bn[12];
#pragma unroll
    for (int q = 0; q < 12; ++q){
        int j = p0 + q*256 + t;
        unsigned kk = 0xFFFFFFFFu;
        int bin = -1;
        if (j < p1){
            float4 pp = pp4[j];
            float dt = ax*pp.x + ay*pp.y + az*pp.z;
            float d2 = fmaxf((a2 + pp.w) - 2.0f*dt, 0.f);
            if (d2 <= 9.0f){
                kk = __float_as_uint(d2);
                bin = (int)(d2 * BINSCALE);
                if (bin > 255) bin = 255;
            }
        }
        kb[q] = kk; jj[q] = j; bn[q] = bin;
    }
    h1[t] = 0;
    if (t == 0){ s_nsel = 0; s_nbound = 0; }
    __syncthreads();
#pragma unroll
    for (int q = 0; q < 12; ++q)
        if (bn[q] >= 0) atomicAdd(&h1[bn[q]], 1);
    __syncthreads();
    if (t < 64){
        int base = t*4;
        int a0 = h1[base], a1 = h1[base+1], a2i = h1[base+2], a3 = h1[base+3];
        int lsum = a0 + a1 + a2i + a3;
        int sc = lsum;
#pragma unroll
        for (int off = 1; off < 64; off <<= 1){
            int v = __shfl_up(sc, off);
            if (lane >= off) sc += v;
        }
        int ex = sc - lsum;
        h1[base]   = ex + a0;
        h1[base+1] = ex + a0 + a1;
        h1[base+2] = ex + a0 + a1 + a2i;
        h1[base+3] = sc;
        if (t == 63) s_info[3] = sc;
    }
    __syncthreads();
    const int total = s_info[3];
    const int kth = (total < KNN) ? total : KNN;
    if (kth > 0){
        int cum  = h1[t];
        int prev = (t == 0) ? 0 : h1[t-1];
        if (cum >= kth && prev < kth){ s_info[0] = t; }
    }
    __syncthreads();
    const int B = s_info[0];
    if (kth > 0){
#pragma unroll
        for (int q = 0; q < 12; ++q){
            if (bn[q] < 0) continue;
            if (bn[q] < B){
                int pos = atomicAdd(&s_nsel, 1);
                src_out[i*KNN + pos] = jj[q];
            } else if (bn[q] == B){
                int bi = atomicAdd(&s_nbound, 1);
                if (bi < 512) s_bound[bi] = ((unsigned long long)kb[q] << 32) | (unsigned)jj[q];
            }
        }
    }
    __syncthreads();
    const int base_n = s_nsel;
    const int R = kth - base_n;
    if (t < 64 && R > 0){
        int L = s_nbound; if (L > 512) L = 512;
        for (int r = 0; r < R; ++r){
            unsigned long long m = ~0ull;
            for (int idx = lane; idx < L; idx += 64) m = ullmin2(m, s_bound[idx]);
#pragma unroll
            for (int off = 32; off >= 1; off >>= 1)
                m = ullmin2(m, (unsigned long long)__shfl_xor((unsigned long long)m, off));
            if (lane == 0) src_out[i*KNN + base_n + r] = (int)(unsigned)(m & 0xFFFFFFFFull);
            for (int idx = lane; idx < L; idx += 64)
                if (s_bound[idx] == m) s_bound[idx] = ~0ull;
        }
    }
    if (t < KNN && t >= kth) src_out[i*KNN + t] = -1;
}

// ---------------------------------------------------------------- CSR prefix + frag centers + scatter (merged, 1 block x 1024)
__global__ __launch_bounds__(1024) void k_csr_prefix(const float* __restrict__ cnt,
                                                     const float* __restrict__ tsum,
                                                     const float* __restrict__ isum,
                                                     const int* __restrict__ fid,
                                                     int* __restrict__ csr_off,
                                                     int* __restrict__ csr_atom,
                                                     float* __restrict__ tfrag,
                                                     float* __restrict__ ifin){
    __shared__ int s[1024];
    __shared__ int s_cur[1024];
    int t = threadIdx.x;
    float cn_raw = cnt[t];
    int v = (int)cn_raw;
    s[t] = v;
    {
        float cn = fmaxf(cn_raw, 1.f);
        tfrag[t*3+0] = tsum[t*3+0] / cn;
        tfrag[t*3+1] = tsum[t*3+1] / cn;
        tfrag[t*3+2] = tsum[t*3+2] / cn;
        float tr  = isum[t*9+0] + isum[t*9+4] + isum[t*9+8];
        float add = 1e-4f * fmaxf(tr, 1.f);
#pragma unroll
        for (int q = 0; q < 9; ++q){
            float vv = isum[t*9+q];
            if (q == 0 || q == 4 || q == 8) vv += add;
            ifin[t*9+q] = vv;
        }
    }
    __syncthreads();
    for (int off = 1; off < 1024; off <<= 1){
        int x = (t >= off) ? s[t-off] : 0;
        __syncthreads();
        s[t] += x;
        __syncthreads();
    }
    int incl = s[t];
    int excl = incl - v;
    csr_off[t] = excl;
    s_cur[t] = excl;
    if (t == 1023) csr_off[1024] = incl;
    __syncthreads();
#pragma unroll
    for (int it = 0; it < 8; ++it){
        int a = it*1024 + t;
        int f = fid[a];
        int pos = atomicAdd(&s_cur[f], 1);
        csr_atom[pos] = a;
    }
}

// ---------------------------------------------------------------- common[a][n] = b1[n] + [has|temb]_a . W1[144:400]
__global__ __launch_bounds__(256) void k_ctx(const float* __restrict__ has_,
                                             const float* __restrict__ temb,
                                             const short* __restrict__ W1cp,
                                             const float* __restrict__ b1,
                                             float* __restrict__ common){
    __shared__ __align__(16) char s_a[64*512];
    const int t = threadIdx.x, l = t & 63, w = t >> 6, g = l >> 4;
    const int a0 = blockIdx.x * 64;
    {
        int r = t & 63, seg = t >> 6;
        const float* srcp = (seg < 2) ? (has_ + (size_t)(a0 + r)*128 + seg*64)
                                      : (temb + (size_t)(a0 + r)*128 + (seg - 2)*64);
#pragma unroll
        for (int q = 0; q < 16; ++q){
            float4 x = *(const float4*)(srcp + q*4);
            int col = seg*64 + q*4;
            int off = (r*512 + col*2) ^ ((r & 7) << 4);
            *(unsigned*)(s_a + off)     = f2bf2(x.x, x.y);
            *(unsigned*)(s_a + off + 4) = f2bf2(x.z, x.w);
        }
    }
    __syncthreads();
    f32x4 acc[4][4];
#pragma unroll
    for (int mt = 0; mt < 4; ++mt)
#pragma unroll
        for (int nt = 0; nt < 4; ++nt) acc[mt][nt] = (f32x4){0.f,0.f,0.f,0.f};
    for (int ks = 0; ks < 8; ++ks){
        bf16x8 afr[4];
#pragma unroll
        for (int mt = 0; mt < 4; ++mt){
            int row = mt*16 + (l & 15);
            int off = (row*512 + ks*64 + g*16) ^ ((row & 7) << 4);
            afr[mt] = *(const bf16x8*)(s_a + off);
        }
#pragma unroll
        for (int nt = 0; nt < 4; ++nt){
            bf16x8 b = *(const bf16x8*)(W1cp + ((size_t)((ks*16 + (w*4 + nt))*64 + l))*8);
#pragma unroll
            for (int mt = 0; mt < 4; ++mt)
                acc[mt][nt] = __builtin_amdgcn_mfma_f32_16x16x32_bf16(afr[mt], b, acc[mt][nt], 0, 0, 0);
        }
    }
#pragma unroll
    for (int nt = 0; nt < 4; ++nt){
        int col = w*64 + nt*16 + (l & 15);
        float bb = b1[col];
#pragma unroll
        for (int mt = 0; mt < 4; ++mt)
#pragma unroll
            for (int r = 0; r < 4; ++r){
                int row = mt*16 + g*4 + r;
                common[(size_t)(a0 + row)*256 + col] = acc[mt][nt][r] + bb;
            }
    }
}

// ---------------------------------------------------------------- residue->atom conv (512 thr = 8 waves = 1 atom)
#define ES_STR 336   // bytes per es row (160 bf16 + 8 pad)
__global__ __launch_bounds__(512, 2) void k_ra3(
    const float* __restrict__ apos, const float* __restrict__ ppos,
    const short* __restrict__ hpsB, const short* __restrict__ hpvT,
    const short* __restrict__ W1p, const short* __restrict__ W2p,
    const short* __restrict__ Wsp, const short* __restrict__ Wvp,
    const float* __restrict__ common, const float* __restrict__ b2,
    const int* __restrict__ src,
    short* __restrict__ msR, short* __restrict__ mvR)
{
    __shared__ __align__(16) char s_es[32*ES_STR];
    __shared__ __align__(16) char s_h1[32*512];
    __shared__ __align__(16) char s_hpv[3*4096];
    __shared__ float s_unit[32][3];

    const int t = threadIdx.x;
    const int i = blockIdx.x;
    const int l = t & 63, w = t >> 6, g = l >> 4, r0 = l & 15;
    const int xm = (r0 & 7) << 4;
    float* s_mvA = (float*)s_es;
    float* s_mvB = s_mvA + 192;

    {
        const int e = t >> 4, sub = t & 15;
        const int j = src[i*KNN + e];
        float dx = 0.f, dy = 0.f, dz = 0.f, dist = 0.f;
        if (j >= 0){
            dx = apos[i*3+0] - ppos[j*3+0];
            dy = apos[i*3+1] - ppos[j*3+1];
            dz = apos[i*3+2] - ppos[j*3+2];
            dist = sqrtf(dx*dx + dy*dy + dz*dz);
        }
        if (sub == 0){
            float inv = 1.f / (dist + 1e-8f);
            s_unit[e][0] = dx*inv; s_unit[e][1] = dy*inv; s_unit[e][2] = dz*inv;
        }
        if (sub < 2){
            const float gamma = 16.0f / 6.0f;
#pragma unroll
            for (int q = 0; q < 4; ++q){
                int kk = sub*8 + q*2;
                float mu0  = 0.4f * (float)kk;
                float mu1  = 0.4f * (float)(kk+1);
                float a0 = gamma * (dist - mu0);
                float a1 = gamma * (dist - mu1);
                float e0 = (j >= 0) ? __expf(-(a0*a0)) : 0.f;
                float e1 = (j >= 0) ? __expf(-(a1*a1)) : 0.f;
                *(unsigned*)(s_es + e*ES_STR + kk*2) = f2bf2(e0, e1);
            }
        }
        if (sub < 8) *(int*)(s_es + e*ES_STR + 288 + sub*4) = 0;
        const bf16x8 zv = (bf16x8){0,0,0,0,0,0,0,0};
        {
            bf16x8 hc = (j >= 0) ? *(const bf16x8*)(hpsB + (size_t)j*128 + sub*8) : zv;
            *(bf16x8*)(s_es + e*ES_STR + 32 + sub*16) = hc;
        }
        const int em = (e & 7) << 4;
        {
            bf16x8 c0 = (j >= 0) ? *(const bf16x8*)(hpvT + (size_t)j*192 + sub*8) : zv;
            *(bf16x8*)(s_hpv + (sub>>3)*4096 + e*128 + (((sub&7)<<4) ^ em)) = c0;
            if (sub < 8){
                bf16x8 c1 = (j >= 0) ? *(const bf16x8*)(hpvT + (size_t)j*192 + (16+sub)*8) : zv;
                *(bf16x8*)(s_hpv + 2*4096 + e*128 + ((sub<<4) ^ em)) = c1;
            }
        }
    }
    __syncthreads();

    f32x4 acc1[2][2];
#pragma unroll
    for (int mt = 0; mt < 2; ++mt)
#pragma unroll
        for (int nt = 0; nt < 2; ++nt) acc1[mt][nt] = (f32x4){0.f,0.f,0.f,0.f};
    for (int ks = 0; ks < 5; ++ks){
        bf16x8 a0 = *(const bf16x8*)(s_es + r0*ES_STR + ks*64 + g*16);
        bf16x8 a1 = *(const bf16x8*)(s_es + (16 + r0)*ES_STR + ks*64 + g*16);
#pragma unroll
        for (int nt = 0; nt < 2; ++nt){
            bf16x8 b = *(const bf16x8*)(W1p + ((size_t)((ks*16 + (w*2 + nt))*64 + l))*8);
            acc1[0][nt] = __builtin_amdgcn_mfma_f32_16x16x32_bf16(a0, b, acc1[0][nt], 0, 0, 0);
            acc1[1][nt] = __builtin_amdgcn_mfma_f32_16x16x32_bf16(a1, b, acc1[1][nt], 0, 0, 0);
        }
    }

#pragma unroll
    for (int nt = 0; nt < 2; ++nt){
        int col = w*32 + nt*16 + r0;
        float cm = common[(size_t)i*256 + col];
#pragma unroll
        for (int mt = 0; mt < 2; ++mt)
#pragma unroll
            for (int r = 0; r < 4; ++r){
                float v = silu_f(acc1[mt][nt][r] + cm);
                int row = mt*16 + g*4 + r;
                int off = (row*512 + col*2) ^ ((row & 7) << 4);
                *(short*)(s_h1 + off) = f2bf(v);
            }
    }

    f32x4 accxs[2][2];
#pragma unroll
    for (int mt = 0; mt < 2; ++mt)
#pragma unroll
        for (int nt = 0; nt < 2; ++nt) accxs[mt][nt] = (f32x4){0.f,0.f,0.f,0.f};
    if (w < 4){
        for (int ks = 0; ks < 4; ++ks){
            bf16x8 a0 = *(const bf16x8*)(s_es + r0*ES_STR + 32 + ks*64 + g*16);
            bf16x8 a1 = *(const bf16x8*)(s_es + (16 + r0)*ES_STR + 32 + ks*64 + g*16);
#pragma unroll
            for (int nt = 0; nt < 2; ++nt){
                bf16x8 b = *(const bf16x8*)(Wsp + ((size_t)((ks*8 + (w*2 + nt))*64 + l))*8);
                accxs[0][nt] = __builtin_amdgcn_mfma_f32_16x16x32_bf16(a0, b, accxs[0][nt], 0, 0, 0);
                accxs[1][nt] = __builtin_amdgcn_mfma_f32_16x16x32_bf16(a1, b, accxs[1][nt], 0, 0, 0);
            }
        }
    }
    __syncthreads();

    f32x4 accw[2][2];
#pragma unroll
    for (int mt = 0; mt < 2; ++mt)
#pragma unroll
        for (int nt = 0; nt < 2; ++nt) accw[mt][nt] = (f32x4){0.f,0.f,0.f,0.f};
    for (int ks = 0; ks < 8; ++ks){
        int off0 = (r0*512 + ks*64 + g*16) ^ xm;
        bf16x8 a0 = *(const bf16x8*)(s_h1 + off0);
        bf16x8 a1 = *(const bf16x8*)(s_h1 + off0 + 8192);
#pragma unroll
        for (int nt = 0; nt < 2; ++nt){
            bf16x8 b = *(const bf16x8*)(W2p + ((size_t)((ks*16 + (w*2 + nt))*64 + l))*8);
            accw[0][nt] = __builtin_amdgcn_mfma_f32_16x16x32_bf16(a0, b, accw[0][nt], 0, 0, 0);
            accw[1][nt] = __builtin_amdgcn_mfma_f32_16x16x32_bf16(a1, b, accw[1][nt], 0, 0, 0);
        }
    }
    float b2v[2];
#pragma unroll
    for (int nt = 0; nt < 2; ++nt) b2v[nt] = b2[w*32 + nt*16 + r0];

    if (w < 4){
#pragma unroll
        for (int nt = 0; nt < 2; ++nt){
            float p = 0.f;
#pragma unroll
            for (int mt = 0; mt < 2; ++mt)
#pragma unroll
                for (int r = 0; r < 4; ++r)
                    p = fmaf(accw[mt][nt][r] + b2v[nt], accxs[mt][nt][r], p);
            p += __shfl_xor(p, 16);
            p += __shfl_xor(p, 32);
            if (l < 16) msR[(size_t)i*128 + w*32 + nt*16 + r0] = f2bf(p);
        }
    } else if (w < 6){
        bf16x8 bv[2][2];
#pragma unroll
        for (int ks = 0; ks < 2; ++ks)
#pragma unroll
            for (int nt = 0; nt < 2; ++nt)
                bv[ks][nt] = *(const bf16x8*)(Wvp + ((size_t)((ks*4 + (w-4)*2 + nt)*64 + l))*8);
#pragma unroll
        for (int c = 0; c < 3; ++c){
            f32x4 accxv[2][2];
#pragma unroll
            for (int mt = 0; mt < 2; ++mt)
#pragma unroll
                for (int nt = 0; nt < 2; ++nt) accxv[mt][nt] = (f32x4){0.f,0.f,0.f,0.f};
#pragma unroll
            for (int ks = 0; ks < 2; ++ks){
                int off0 = c*4096 + r0*128 + ((ks*64 + g*16) ^ xm);
                bf16x8 a0 = *(const bf16x8*)(s_hpv + off0);
                bf16x8 a1 = *(const bf16x8*)(s_hpv + off0 + 2048);
#pragma unroll
                for (int nt = 0; nt < 2; ++nt){
                    accxv[0][nt] = __builtin_amdgcn_mfma_f32_16x16x32_bf16(a0, bv[ks][nt], accxv[0][nt], 0, 0, 0);
                    accxv[1][nt] = __builtin_amdgcn_mfma_f32_16x16x32_bf16(a1, bv[ks][nt], accxv[1][nt], 0, 0, 0);
                }
            }
#pragma unroll
            for (int nt = 0; nt < 2; ++nt){
                float p = 0.f;
#pragma unroll
                for (int mt = 0; mt < 2; ++mt)
#pragma unroll
                    for (int r = 0; r < 4; ++r)
                        p = fmaf(accw[mt][nt][r] + b2v[nt], accxv[mt][nt][r], p);
                p += __shfl_xor(p, 16);
                p += __shfl_xor(p, 32);
                if (l < 16) s_mvA[c*64 + (w-4)*32 + nt*16 + r0] = p;
            }
        }
    } else {
        float uu[8][3];
#pragma unroll
        for (int mt = 0; mt < 2; ++mt)
#pragma unroll
            for (int r = 0; r < 4; ++r){
                int e = mt*16 + g*4 + r;
#pragma unroll
                for (int c = 0; c < 3; ++c) uu[mt*4+r][c] = s_unit[e][c];
            }
#pragma unroll
        for (int c = 0; c < 3; ++c)
#pragma unroll
            for (int nt = 0; nt < 2; ++nt){
                float p = 0.f;
#pragma unroll
                for (int mt = 0; mt < 2; ++mt)
#pragma unroll
                    for (int r = 0; r < 4; ++r)
                        p = fmaf(accw[mt][nt][r] + b2v[nt], uu[mt*4+r][c], p);
                p += __shfl_xor(p, 16);
                p += __shfl_xor(p, 32);
                if (l < 16) s_mvB[c*64 + (w-6)*32 + nt*16 + r0] = p;
            }
    }
    __syncthreads();

    if (t < 192){
        int wi = t & 63, cc = t >> 6;
        float v = s_mvA[cc*64 + wi] + s_mvB[cc*64 + wi];
        mvR[((size_t)i*3 + cc)*64 + wi] = f2bf(v);
    }
}

// ---------------------------------------------------------------- batched output transforms (MFMA) + bf16 dual-write
__global__ __launch_bounds__(256) void k_ra_out(
    const short* __restrict__ msR, const short* __restrict__ mvR,
    const short* __restrict__ Wosp, const short* __restrict__ Wovp,
    const float* __restrict__ has_, const float* __restrict__ hav,
    float* __restrict__ out,
    short* __restrict__ haB, short* __restrict__ havT)
{
    const int t = threadIdx.x, l = t & 63, w = t >> 6, g = l >> 4, r0 = l & 15;
    const int a0 = blockIdx.x * 32;

    f32x4 acc[2][2];
#pragma unroll
    for (int mt = 0; mt < 2; ++mt)
#pragma unroll
        for (int nt = 0; nt < 2; ++nt) acc[mt][nt] = (f32x4){0.f,0.f,0.f,0.f};
    for (int ks = 0; ks < 4; ++ks){
        bf16x8 af0 = *(const bf16x8*)(msR + ((size_t)(a0 + r0)*128 + ks*32 + g*8));
        bf16x8 af1 = *(const bf16x8*)(msR + ((size_t)(a0 + 16 + r0)*128 + ks*32 + g*8));
#pragma unroll
        for (int nt = 0; nt < 2; ++nt){
            bf16x8 b = *(const bf16x8*)(Wosp + ((size_t)((ks*8 + (w*2 + nt))*64 + l))*8);
            acc[0][nt] = __builtin_amdgcn_mfma_f32_16x16x32_bf16(af0, b, acc[0][nt], 0, 0, 0);
            acc[1][nt] = __builtin_amdgcn_mfma_f32_16x16x32_bf16(af1, b, acc[1][nt], 0, 0, 0);
        }
    }
#pragma unroll
    for (int nt = 0; nt < 2; ++nt){
        int col = w*32 + nt*16 + r0;
#pragma unroll
        for (int mt = 0; mt < 2; ++mt)
#pragma unroll
            for (int r = 0; r < 4; ++r){
                int a = a0 + mt*16 + g*4 + r;
                float val = has_[(size_t)a*128 + col] + silu_f(acc[mt][nt][r]);
                out[(size_t)a*OUTC + col] = val;
                haB[(size_t)a*128 + col] = f2bf(val);
            }
    }

    f32x4 accv[6];
#pragma unroll
    for (int mt = 0; mt < 6; ++mt) accv[mt] = (f32x4){0.f,0.f,0.f,0.f};
    for (int ks = 0; ks < 2; ++ks){
        bf16x8 b = *(const bf16x8*)(Wovp + ((size_t)((ks*4 + w)*64 + l))*8);
#pragma unroll
        for (int mt = 0; mt < 6; ++mt){
            bf16x8 af = *(const bf16x8*)(mvR + ((size_t)(a0*3 + mt*16 + r0)*64 + ks*32 + g*8));
            accv[mt] = __builtin_amdgcn_mfma_f32_16x16x32_bf16(af, b, accv[mt], 0, 0, 0);
        }
    }
    const int wi = w*16 + r0;
#pragma unroll
    for (int mt = 0; mt < 6; ++mt)
#pragma unroll
        for (int r = 0; r < 4; ++r){
            int R = mt*16 + g*4 + r;
            int a = a0 + R/3, c = R - (R/3)*3;
            float val = hav[(size_t)a*192 + wi*3 + c] + accv[mt][r];
            out[(size_t)a*OUTC + 128 + wi*3 + c] = val;
            havT[(size_t)a*192 + c*64 + wi] = f2bf(val);
        }
}

// ---------------------------------------------------------------- atom->frag conv, MFMA (1 block = 16 atoms, 2 blk/CU)
#define AES_STR 848  // bytes per es row (416 bf16 + 8 pad)
__global__ __launch_bounds__(256, 2) void k_af2(
    const float* __restrict__ apos, const float* __restrict__ tfrag,
    const short* __restrict__ haB, const short* __restrict__ hfsB,
    const short* __restrict__ tembB, const short* __restrict__ havT,
    const short* __restrict__ W1p, const float* __restrict__ b1,
    const short* __restrict__ W2p, const float* __restrict__ b2,
    const short* __restrict__ Wsp, const short* __restrict__ Wvp,
    const int* __restrict__ fragid,
    short* __restrict__ msA, short* __restrict__ mvA)
{
    __shared__ __align__(16) char s_es[16*AES_STR];
    __shared__ __align__(16) char s_h1[16*512];
    __shared__ __align__(16) char s_pv[3*2048];
    __shared__ float s_unit[16][3];
    float* s_upr = (float*)s_es;

    const int t = threadIdx.x, a0 = blockIdx.x*16;
    const int l = t & 63, w = t >> 6, g = l >> 4, r0 = l & 15;
    const int xm = (r0 & 7) << 4;

    {
        const int e = t >> 4, sub = t & 15;
        const int a = a0 + e;
        const int f = fragid[a];
        float rx = apos[a*3+0] - tfrag[f*3+0];
        float ry = apos[a*3+1] - tfrag[f*3+1];
        float rz = apos[a*3+2] - tfrag[f*3+2];
        float dist = sqrtf(rx*rx + ry*ry + rz*rz);
        if (sub == 0){
            float inv = 1.f / (dist + 1e-8f);
            s_unit[e][0] = rx*inv; s_unit[e][1] = ry*inv; s_unit[e][2] = rz*inv;
        }
        if (sub < 2){
            const float gamma = 16.0f / 6.0f;
#pragma unroll
            for (int q = 0; q < 4; ++q){
                int kk = sub*8 + q*2;
                float mu0  = 0.4f * (float)kk;
                float mu1  = 0.4f * (float)(kk+1);
                float a0f = gamma * (dist - mu0);
                float a1f = gamma * (dist - mu1);
                *(unsigned*)(s_es + e*AES_STR + kk*2) = f2bf2(__expf(-(a0f*a0f)), __expf(-(a1f*a1f)));
            }
        }
        *(bf16x8*)(s_es + e*AES_STR + 32  + sub*16) = *(const bf16x8*)(haB  + (size_t)a*128 + sub*8);
        *(bf16x8*)(s_es + e*AES_STR + 288 + sub*16) = *(const bf16x8*)(hfsB + (size_t)f*128 + sub*8);
        *(bf16x8*)(s_es + e*AES_STR + 544 + sub*16) = *(const bf16x8*)(tembB + (size_t)a*128 + sub*8);
        *(short*)(s_es + e*AES_STR + 800 + sub*2) = 0;
        const int em = (e & 7) << 4;
        {
            bf16x8 c0 = *(const bf16x8*)(havT + (size_t)a*192 + sub*8);
            *(bf16x8*)(s_pv + (sub>>3)*2048 + e*128 + (((sub&7)<<4) ^ em)) = c0;
            if (sub < 8){
                bf16x8 c1 = *(const bf16x8*)(havT + (size_t)a*192 + (16+sub)*8);
                *(bf16x8*)(s_pv + 2*2048 + e*128 + ((sub<<4) ^ em)) = c1;
            }
        }
    }
    __syncthreads();

    f32x4 acc1[4];
#pragma unroll
    for (int nt = 0; nt < 4; ++nt) acc1[nt] = (f32x4){0.f,0.f,0.f,0.f};
    for (int ks = 0; ks < 13; ++ks){
        bf16x8 a0f = *(const bf16x8*)(s_es + r0*AES_STR + ks*64 + g*16);
#pragma unroll
        for (int nt = 0; nt < 4; ++nt){
            bf16x8 b = *(const bf16x8*)(W1p + ((size_t)((ks*16 + (w*4 + nt))*64 + l))*8);
            acc1[nt] = __builtin_amdgcn_mfma_f32_16x16x32_bf16(a0f, b, acc1[nt], 0, 0, 0);
        }
    }
#pragma unroll
    for (int nt = 0; nt < 4; ++nt){
        int col = w*64 + nt*16 + r0;
        float bb = b1[col];
#pragma unroll
        for (int r = 0; r < 4; ++r){
            float v = silu_f(acc1[nt][r] + bb);
            int row = g*4 + r;
            int off = (row*512 + col*2) ^ ((row & 7) << 4);
            *(short*)(s_h1 + off) = f2bf(v);
        }
    }
    f32x4 accxs[4];
#pragma unroll
    for (int nt = 0; nt < 4; ++nt) accxs[nt] = (f32x4){0.f,0.f,0.f,0.f};
    if (w < 2){
        for (int ks = 0; ks < 4; ++ks){
            bf16x8 a0f = *(const bf16x8*)(s_es + r0*AES_STR + 32 + ks*64 + g*16);
#pragma unroll
            for (int nt = 0; nt < 4; ++nt){
                bf16x8 b = *(const bf16x8*)(Wsp + ((size_t)((ks*8 + (w*4 + nt))*64 + l))*8);
                accxs[nt] = __builtin_amdgcn_mfma_f32_16x16x32_bf16(a0f, b, accxs[nt], 0, 0, 0);
            }
        }
    }
    __syncthreads();

    f32x4 accw[4];
#pragma unroll
    for (int nt = 0; nt < 4; ++nt) accw[nt] = (f32x4){0.f,0.f,0.f,0.f};
    for (int ks = 0; ks < 8; ++ks){
        int off0 = (r0*512 + ks*64 + g*16) ^ xm;
        bf16x8 a0f = *(const bf16x8*)(s_h1 + off0);
#pragma unroll
        for (int nt = 0; nt < 4; ++nt){
            bf16x8 b = *(const bf16x8*)(W2p + ((size_t)((ks*16 + (w*4 + nt))*64 + l))*8);
            accw[nt] = __builtin_amdgcn_mfma_f32_16x16x32_bf16(a0f, b, accw[nt], 0, 0, 0);
        }
    }
    float b2v[4];
#pragma unroll
    for (int nt = 0; nt < 4; ++nt) b2v[nt] = b2[w*64 + nt*16 + r0];

    if (w == 3){
        float uu[4][3];
#pragma unroll
        for (int r = 0; r < 4; ++r){
            int e = g*4 + r;
#pragma unroll
            for (int c = 0; c < 3; ++c) uu[r][c] = s_unit[e][c];
        }
#pragma unroll
        for (int nt = 0; nt < 4; ++nt){
            int wi = nt*16 + r0;
#pragma unroll
            for (int r = 0; r < 4; ++r){
                int e = g*4 + r;
                float gate = accw[nt][r] + b2v[nt];
#pragma unroll
                for (int c = 0; c < 3; ++c)
                    s_upr[e*192 + wi*3 + c] = gate * uu[r][c];
            }
        }
    }
    __syncthreads();

    if (w < 2){
#pragma unroll
        for (int nt = 0; nt < 4; ++nt){
            int col = w*64 + nt*16 + r0;
#pragma unroll
            for (int r = 0; r < 4; ++r){
                int e = g*4 + r;
                float p = (accw[nt][r] + b2v[nt]) * accxs[nt][r];
                msA[(size_t)(a0 + e)*128 + col] = f2bf(p);
            }
        }
    } else if (w == 2){
        bf16x8 bv[2][4];
#pragma unroll
        for (int ks = 0; ks < 2; ++ks)
#pragma unroll
            for (int nt = 0; nt < 4; ++nt)
                bv[ks][nt] = *(const bf16x8*)(Wvp + ((size_t)((ks*4 + nt)*64 + l))*8);
#pragma unroll
        for (int c = 0; c < 3; ++c){
            f32x4 accxv[4];
#pragma unroll
            for (int nt = 0; nt < 4; ++nt) accxv[nt] = (f32x4){0.f,0.f,0.f,0.f};
#pragma unroll
            for (int ks = 0; ks < 2; ++ks){
                int off0 = c*2048 + r0*128 + ((ks*64 + g*16) ^ xm);
                bf16x8 a0f = *(const bf16x8*)(s_pv + off0);
#pragma unroll
                for (int nt = 0; nt < 4; ++nt)
                    accxv[nt] = __builtin_amdgcn_mfma_f32_16x16x32_bf16(a0f, bv[ks][nt], accxv[nt], 0, 0, 0);
            }
#pragma unroll
            for (int nt = 0; nt < 4; ++nt){
                int wi = nt*16 + r0;
#pragma unroll
                for (int r = 0; r < 4; ++r){
                    int e = g*4 + r;
                    float p = (accw[nt][r] + b2v[nt]) * accxv[nt][r]
                            + s_upr[e*192 + wi*3 + c];
                    mvA[(size_t)(a0 + e)*192 + wi*3 + c] = f2bf(p);
                }
            }
        }
    }
}

// ---------------------------------------------------------------- frag update (CSR gather + transform + direct scatter)
__global__ __launch_bounds__(256) void k_fragupd(
    const int* __restrict__ csr_off, const int* __restrict__ csr_atom,
    const short* __restrict__ msA, const short* __restrict__ mvA,
    const float* __restrict__ hfs_in, const float* __restrict__ hfv_in,
    const float* __restrict__ Wfs, const float* __restrict__ Wfv,
    const float* __restrict__ ifin,
    float* __restrict__ out)
{
    __shared__ __align__(16) float s_fs[128];
    __shared__ __align__(16) float s_fv[192];
    const int f = blockIdx.x, t = threadIdx.x;
    const int n0 = csr_off[f], n1 = csr_off[f+1];
    if (t < 128){
        float s = 0.f;
        for (int n = n0; n < n1; ++n){
            int a = csr_atom[n];
            s += bf2f(msA[(size_t)a*128 + t]);
        }
        s_fs[t] = s;
    }
    if (t >= 64){
        int idx = t - 64;
        float s = 0.f;
        for (int n = n0; n < n1; ++n){
            int a = csr_atom[n];
            s += bf2f(mvA[(size_t)a*192 + idx]);
        }
        s_fv[(idx % 3)*64 + (idx / 3)] = s;
    }
    __syncthreads();
    if (t < 128){
        float o = 0.f;
        for (int k = 0; k < 128; k += 4){
            const float* wr = &Wfs[k*128 + t];
            float4 m4 = *(const float4*)&s_fs[k];
            o = fmaf(m4.x, wr[0],   o);
            o = fmaf(m4.y, wr[128], o);
            o = fmaf(m4.z, wr[256], o);
            o = fmaf(m4.w, wr[384], o);
        }
        float val = hfs_in[f*128 + t] + silu_f(o);
        for (int n = n0; n < n1; ++n)
            out[(size_t)csr_atom[n]*OUTC + 320 + t] = val;
    }
    if (t < 192){
        const int wi = t & 63, cc = t >> 6;
        float o = 0.f;
        for (int v = 0; v < 64; v += 4){
            const float* wr = &Wfv[v*64 + wi];
            float4 m4 = *(const float4*)&s_fv[cc*64 + v];
            o = fmaf(m4.x, wr[0],   o);
            o = fmaf(m4.y, wr[64],  o);
            o = fmaf(m4.z, wr[128], o);
            o = fmaf(m4.w, wr[192], o);
        }
        float val = hfv_in[f*192 + wi*3 + cc] + o;
        for (int n = n0; n < n1; ++n)
            out[(size_t)csr_atom[n]*OUTC + 448 + wi*3 + cc] = val;
    } else if (t < 201){
        int q = t - 192;
        float val = ifin[f*9 + q];
        for (int n = n0; n < n1; ++n)
            out[(size_t)csr_atom[n]*OUTC + 640 + q] = val;
    }
}

// ----------------------------------------------------------------
extern "C" void kernel_launch(void* const* d_in, const int* in_sizes, int n_in,
                              void* d_out, int out_size, void* d_ws, size_t ws_size,
                              hipStream_t stream)
{
    const float* atom_pos   = (const float*)d_in[0];
    const float* prot_pos   = (const float*)d_in[1];
    const float* local_pos  = (const float*)d_in[2];
    const float* h_atom_s   = (const float*)d_in[3];
    const float* h_atom_v   = (const float*)d_in[4];
    const float* h_prot_s   = (const float*)d_in[5];
    const float* h_prot_v   = (const float*)d_in[6];
    const float* h_frag_s   = (const float*)d_in[7];
    const float* h_frag_v   = (const float*)d_in[8];
    const float* t_emb      = (const float*)d_in[9];
    const float* W1_ra = (const float*)d_in[10]; const float* b1_ra = (const float*)d_in[11];
    const float* W2_ra = (const float*)d_in[12]; const float* b2_ra = (const float*)d_in[13];
    const float* Ws_ra = (const float*)d_in[14]; const float* Wv_ra = (const float*)d_in[15];
    const float* W1_af = (const float*)d_in[16]; const float* b1_af = (const float*)d_in[17];
    const float* W2_af = (const float*)d_in[18]; const float* b2_af = (const float*)d_in[19];
    const float* Ws_af = (const float*)d_in[20]; const float* Wv_af = (const float*)d_in[21];
    const float* Wo_s  = (const float*)d_in[22]; const float* Wo_v  = (const float*)d_in[23];
    const float* Wf_s  = (const float*)d_in[24]; const float* Wf_v  = (const float*)d_in[25];
    const int* fragment_id = (const int*)d_in[26];
    const int* atom_batch  = (const int*)d_in[27];
    const int* prot_batch  = (const int*)d_in[28];
    float* out = (float*)d_out;

    // ---- workspace layout ----
    float* cnt   = (float*)d_ws;                 // 1024   (zeroed)
    float* tsum  = cnt  + 1024;                  // 3072   (zeroed)
    float* isum  = tsum + 3072;                  // 9216   (zeroed)
    float* tfrag = isum + 9216;                  // 3072
    float* ifin  = tfrag + 3072;                 // 9216
    float* hfs   = ifin + 9216;                  // 131072 (unused, layout stability)
    float* hfv   = hfs  + 1024*128;              // 196608 (unused)
    int*   pstart   = (int*)(hfv + 1024*192);    // 16
    int*   src      = pstart + 16;               // 262144
    int*   csr_off  = src + N_ATOM*KNN;          // 1025
    int*   csr_cur  = csr_off + 1025;            // 1024 (unused)
    int*   csr_atom = csr_cur + 1024;            // 8192
    uintptr_t pal = ((uintptr_t)(csr_atom + 8192) + 127) & ~(uintptr_t)127;
    float* common = (float*)pal;                 // 8192*256 f32 (8 MB)
    // aliases inside common (dead after k_ra3):
    short* msA  = (short*)common;                // 2 MB  (written k_af2)
    short* mvA  = msA + (size_t)8192*128;        // 3 MB  (written k_af2)
    short* havT = mvA + (size_t)8192*192;        // 3 MB  (written k_ra_out)
    short* W1p  = (short*)(common + (size_t)8192*256);
    short* W2p  = W1p  + 40960;
    short* Wsp  = W2p  + 65536;
    short* Wvp  = Wsp  + 16384;
    short* W1cp = Wvp  + 4096;
    short* W1ap = W1cp + 65536;
    short* W2ap = W1ap + 106496;
    short* Wsap = W2ap + 65536;
    short* Wvap = Wsap + 16384;
    short* Wosp = Wvap + 4096;
    short* Wovp = Wosp + 16384;
    short* msR  = Wovp + 4096;                   // 8192*128 bf16 (2 MB)
    short* mvR  = msR + (size_t)8192*128;        // 8192*192 bf16 (3 MB)
    short* hpsB = mvR + (size_t)8192*192;        // 16384*128 bf16 (4 MB)
    short* hpvT = hpsB + (size_t)N_PROT*128;     // 16384*192 bf16 (6 MB)
    short* haB  = hpvT + (size_t)N_PROT*192;     // 8192*128 bf16 (2 MB)
    short* hfsB = haB + (size_t)8192*128;        // 1024*128 bf16 (256 KB)
    short* tembB= hfsB + (size_t)1024*128;       // 8192*128 bf16 (2 MB)
    uintptr_t p4 = ((uintptr_t)(tembB + (size_t)8192*128) + 15) & ~(uintptr_t)15;
    float* ppos4 = (float*)p4;                   // 16384*4 f32 (256 KB)

    size_t zero_bytes = (size_t)(1024 + 3072 + 9216) * sizeof(float);
    hipMemsetAsync(cnt, 0, zero_bytes, stream);

    k_prep    <<<PREP_NB, 256, 0, stream>>>(W1_ra, W2_ra, Ws_ra, Wv_ra, W1_af, W2_af, Ws_af, Wv_af,
                                            Wo_s, Wo_v,
                                            h_prot_s, h_prot_v, h_frag_s, t_emb,
                                            atom_pos, local_pos, prot_pos,
                                            fragment_id, prot_batch,
                                            W1p, W2p, Wsp, Wvp, W1cp, W1ap, W2ap, Wsap, Wvap,
                                            Wosp, Wovp,
                                            hpsB, hpvT, hfsB, tembB, ppos4, pstart,
                                            cnt, tsum, isum);
    k_knn     <<<N_ATOM, 256, 0, stream>>>(atom_pos, ppos4, atom_batch, pstart, src);
    k_ctx     <<<N_ATOM/64, 256, 0, stream>>>(h_atom_s, t_emb, W1cp, b1_ra, common);
    k_csr_prefix<<<1, 1024, 0, stream>>>(cnt, tsum, isum, fragment_id,
                                         csr_off, csr_atom, tfrag, ifin);
    k_ra3     <<<N_ATOM, 512, 0, stream>>>(atom_pos, prot_pos, hpsB, hpvT,
                                           W1p, W2p, Wsp, Wvp, common, b2_ra,
                                           src, msR, mvR);
    k_ra_out  <<<N_ATOM/32, 256, 0, stream>>>(msR, mvR, Wosp, Wovp, h_atom_s, h_atom_v, out,
                                              haB, havT);
    k_af2     <<<N_ATOM/16, 256, 0, stream>>>(atom_pos, tfrag, haB, hfsB, tembB, havT,
                                              W1ap, b1_af, W2ap, b2_af, Wsap, Wvap,
                                              fragment_id, msA, mvA);
    k_fragupd <<<N_FRAG, 256, 0, stream>>>(csr_off, csr_atom, msA, mvA,
                                           h_frag_s, h_frag_v, Wf_s, Wf_v, ifin, out);
}

// Round 23
// 231.115 us; speedup vs baseline: 1.0169x; 1.0169x over previous
//
#include <hip/hip_runtime.h>
#include <hip/hip_bf16.h>

#define N_ATOM 8192
#define N_PROT 16384
#define N_FRAG 1024
#define KNN    32
#define OUTC   649   // 128 + 192 + 128 + 192 + 9

typedef __attribute__((ext_vector_type(8))) short bf16x8;
typedef __attribute__((ext_vector_type(4))) float f32x4;

__device__ __forceinline__ float silu_f(float x){ return x / (1.f + __expf(-x)); }
__device__ __forceinline__ unsigned long long ullmin2(unsigned long long a, unsigned long long b){ return a < b ? a : b; }

__device__ __forceinline__ short f2bf(float x){
    __hip_bfloat16 h = __float2bfloat16(x);
    return *reinterpret_cast<short*>(&h);
}
// packed pair: 2 f32 -> 2 bf16 in one u32
__device__ __forceinline__ unsigned f2bf2(float lo, float hi){
    __hip_bfloat162 h2;
    h2.x = __float2bfloat16(lo);
    h2.y = __float2bfloat16(hi);
    return *reinterpret_cast<unsigned*>(&h2);
}
__device__ __forceinline__ float bf2f(short s){
    return __uint_as_float(((unsigned)(unsigned short)s) << 16);
}

// ================================================================ prep device parts (all elementwise, no LDS)
// pack id ranges (total 50688)
__device__ void dev_pack(int id,
                         const float* __restrict__ W1, const float* __restrict__ W2,
                         const float* __restrict__ Ws, const float* __restrict__ Wv,
                         const float* __restrict__ W1a, const float* __restrict__ W2a,
                         const float* __restrict__ Wsa, const float* __restrict__ Wva,
                         const float* __restrict__ Wos, const float* __restrict__ Wov,
                         short* __restrict__ W1p, short* __restrict__ W2p,
                         short* __restrict__ Wsp, short* __restrict__ Wvp,
                         short* __restrict__ W1cp,
                         short* __restrict__ W1ap, short* __restrict__ W2ap,
                         short* __restrict__ Wsap, short* __restrict__ Wvap,
                         short* __restrict__ Wosp, short* __restrict__ Wovp){
    if (id < 5120){
        int kt = id/1024, rem = id%1024, nt = rem/64, l = rem%64;
#pragma unroll
        for (int jj = 0; jj < 8; ++jj){
            int k = kt*32 + ((l>>4)<<3) + jj, n = nt*16 + (l&15);
            W1p[(size_t)id*8 + jj] = (k < 144) ? f2bf(W1[(size_t)k*256 + n]) : (short)0;
        }
    } else if (id < 13312){
        int id2 = id - 5120;
        int kt = id2/1024, rem = id2%1024, nt = rem/64, l = rem%64;
#pragma unroll
        for (int jj = 0; jj < 8; ++jj){
            int k = kt*32 + ((l>>4)<<3) + jj, n = nt*16 + (l&15);
            W2p[(size_t)id2*8 + jj] = f2bf(W2[(size_t)k*256 + n]);
        }
    } else if (id < 15360){
        int id2 = id - 13312;
        int kt = id2/512, rem = id2%512, nt = rem/64, l = rem%64;
#pragma unroll
        for (int jj = 0; jj < 8; ++jj){
            int k = kt*32 + ((l>>4)<<3) + jj, n = nt*16 + (l&15);
            Wsp[(size_t)id2*8 + jj] = f2bf(Ws[(size_t)k*128 + n]);
        }
    } else if (id < 15872){
        int id2 = id - 15360;
        int kt = id2/256, rem = id2%256, nt = rem/64, l = rem%64;
#pragma unroll
        for (int jj = 0; jj < 8; ++jj){
            int k = kt*32 + ((l>>4)<<3) + jj, n = nt*16 + (l&15);
            Wvp[(size_t)id2*8 + jj] = f2bf(Wv[(size_t)k*64 + n]);
        }
    } else if (id < 24064){
        int id2 = id - 15872;
        int kt = id2/1024, rem = id2%1024, nt = rem/64, l = rem%64;
#pragma unroll
        for (int jj = 0; jj < 8; ++jj){
            int k = kt*32 + ((l>>4)<<3) + jj, n = nt*16 + (l&15);
            W1cp[(size_t)id2*8 + jj] = f2bf(W1[(size_t)(144 + k)*256 + n]);
        }
    } else if (id < 37376){
        int id2 = id - 24064;
        int kt = id2/1024, rem = id2%1024, nt = rem/64, l = rem%64;
#pragma unroll
        for (int jj = 0; jj < 8; ++jj){
            int k = kt*32 + ((l>>4)<<3) + jj, n = nt*16 + (l&15);
            W1ap[(size_t)id2*8 + jj] = (k < 400) ? f2bf(W1a[(size_t)k*256 + n]) : (short)0;
        }
    } else if (id < 45568){
        int id2 = id - 37376;
        int kt = id2/1024, rem = id2%1024, nt = rem/64, l = rem%64;
#pragma unroll
        for (int jj = 0; jj < 8; ++jj){
            int k = kt*32 + ((l>>4)<<3) + jj, n = nt*16 + (l&15);
            W2ap[(size_t)id2*8 + jj] = f2bf(W2a[(size_t)k*256 + n]);
        }
    } else if (id < 47616){
        int id2 = id - 45568;
        int kt = id2/512, rem = id2%512, nt = rem/64, l = rem%64;
#pragma unroll
        for (int jj = 0; jj < 8; ++jj){
            int k = kt*32 + ((l>>4)<<3) + jj, n = nt*16 + (l&15);
            Wsap[(size_t)id2*8 + jj] = f2bf(Wsa[(size_t)k*128 + n]);
        }
    } else if (id < 48128){
        int id2 = id - 47616;
        int kt = id2/256, rem = id2%256, nt = rem/64, l = rem%64;
#pragma unroll
        for (int jj = 0; jj < 8; ++jj){
            int k = kt*32 + ((l>>4)<<3) + jj, n = nt*16 + (l&15);
            Wvap[(size_t)id2*8 + jj] = f2bf(Wva[(size_t)k*64 + n]);
        }
    } else if (id < 50176){
        int id2 = id - 48128;
        int kt = id2/512, rem = id2%512, nt = rem/64, l = rem%64;
#pragma unroll
        for (int jj = 0; jj < 8; ++jj){
            int k = kt*32 + ((l>>4)<<3) + jj, n = nt*16 + (l&15);
            Wosp[(size_t)id2*8 + jj] = f2bf(Wos[(size_t)k*128 + n]);
        }
    } else if (id < 50688){
        int id2 = id - 50176;
        int kt = id2/256, rem = id2%256, nt = rem/64, l = rem%64;
#pragma unroll
        for (int jj = 0; jj < 8; ++jj){
            int k = kt*32 + ((l>>4)<<3) + jj, n = nt*16 + (l&15);
            Wovp[(size_t)id2*8 + jj] = f2bf(Wov[(size_t)k*64 + n]);
        }
    }
}

// ---------------------------------------------------------------- fused prep
#define PREP_B0 198                   // pack: 50688 ids
#define PREP_B1 (PREP_B0 + 2560)     // cvt: N_PROT*(16+24)
#define PREP_B2 (PREP_B1 + 1)        // ranges
#define PREP_B3 (PREP_B2 + 64)       // hfsB: 16384 ids
#define PREP_B4 (PREP_B3 + 512)      // tembB: 131072 ids
#define PREP_B5 (PREP_B4 + 32)       // fragsum: 8192 threads
#define PREP_NB (PREP_B5 + 64)       // ppos4: 16384 ids
__global__ __launch_bounds__(256) void k_prep(
    const float* __restrict__ W1, const float* __restrict__ W2,
    const float* __restrict__ Ws, const float* __restrict__ Wv,
    const float* __restrict__ W1a, const float* __restrict__ W2a,
    const float* __restrict__ Wsa, const float* __restrict__ Wva,
    const float* __restrict__ Wos, const float* __restrict__ Wov,
    const float* __restrict__ hps, const float* __restrict__ hpv,
    const float* __restrict__ hfsF, const float* __restrict__ tembF,
    const float* __restrict__ apos, const float* __restrict__ lpos,
    const float* __restrict__ ppos,
    const int* __restrict__ fid, const int* __restrict__ pbatch,
    short* __restrict__ W1p, short* __restrict__ W2p,
    short* __restrict__ Wsp, short* __restrict__ Wvp,
    short* __restrict__ W1cp,
    short* __restrict__ W1ap, short* __restrict__ W2ap,
    short* __restrict__ Wsap, short* __restrict__ Wvap,
    short* __restrict__ Wosp, short* __restrict__ Wovp,
    short* __restrict__ hpsB, short* __restrict__ hpvT,
    short* __restrict__ hfsB, short* __restrict__ tembB,
    float* __restrict__ ppos4,
    int* __restrict__ pstart,
    float* __restrict__ cnt, float* __restrict__ tsum, float* __restrict__ isum)
{
    const int b = blockIdx.x, t = threadIdx.x;
    if (b < PREP_B0){
        dev_pack(b*256 + t, W1, W2, Ws, Wv, W1a, W2a, Wsa, Wva, Wos, Wov,
                 W1p, W2p, Wsp, Wvp, W1cp, W1ap, W2ap, Wsap, Wvap, Wosp, Wovp);
    } else if (b < PREP_B1){
        int id = (b - PREP_B0)*256 + t;
        if (id < N_PROT*16){
            const float* s = hps + (size_t)id*8;
            float4 x0 = *(const float4*)(s);
            float4 x1 = *(const float4*)(s+4);
            unsigned* d = (unsigned*)(hpsB + (size_t)id*8);
            d[0] = f2bf2(x0.x, x0.y); d[1] = f2bf2(x0.z, x0.w);
            d[2] = f2bf2(x1.x, x1.y); d[3] = f2bf2(x1.z, x1.w);
        } else {
            int id2 = id - N_PROT*16;
            int j = id2 / 24, r = id2 % 24;
            short tmp[8];
#pragma unroll
            for (int u = 0; u < 8; ++u){
                int o = r*8 + u, c = o >> 6, v = o & 63;
                tmp[u] = f2bf(hpv[(size_t)j*192 + v*3 + c]);
            }
            *(bf16x8*)(hpvT + (size_t)j*192 + r*8) = *(bf16x8*)tmp;
        }
    } else if (b < PREP_B2){
        if (t <= 8){
            int lo = 0, hi = N_PROT;
            while (lo < hi){ int mid = (lo + hi) >> 1; if (pbatch[mid] < t) lo = mid + 1; else hi = mid; }
            pstart[t] = lo;
        }
    } else if (b < PREP_B3){
        int id = (b - PREP_B2)*256 + t;
        const float* s = hfsF + (size_t)id*8;
        float4 x0 = *(const float4*)(s);
        float4 x1 = *(const float4*)(s+4);
        unsigned* d = (unsigned*)(hfsB + (size_t)id*8);
        d[0] = f2bf2(x0.x, x0.y); d[1] = f2bf2(x0.z, x0.w);
        d[2] = f2bf2(x1.x, x1.y); d[3] = f2bf2(x1.z, x1.w);
    } else if (b < PREP_B4){
        int id = (b - PREP_B3)*256 + t;
        const float* s = tembF + (size_t)id*8;
        float4 x0 = *(const float4*)(s);
        float4 x1 = *(const float4*)(s+4);
        unsigned* d = (unsigned*)(tembB + (size_t)id*8);
        d[0] = f2bf2(x0.x, x0.y); d[1] = f2bf2(x0.z, x0.w);
        d[2] = f2bf2(x1.x, x1.y); d[3] = f2bf2(x1.z, x1.w);
    } else if (b < PREP_B5){
        int a = (b - PREP_B4)*256 + t;
        if (a < N_ATOM){
            int f = fid[a];
            atomicAdd(&cnt[f], 1.f);
            atomicAdd(&tsum[f*3+0], apos[a*3+0]);
            atomicAdd(&tsum[f*3+1], apos[a*3+1]);
            atomicAdd(&tsum[f*3+2], apos[a*3+2]);
            float x = lpos[a*3+0], y = lpos[a*3+1], z = lpos[a*3+2];
            float r2 = x*x + y*y + z*z;
            atomicAdd(&isum[f*9+0], r2 - x*x);
            atomicAdd(&isum[f*9+1], -(x*y));
            atomicAdd(&isum[f*9+2], -(x*z));
            atomicAdd(&isum[f*9+3], -(y*x));
            atomicAdd(&isum[f*9+4], r2 - y*y);
            atomicAdd(&isum[f*9+5], -(y*z));
            atomicAdd(&isum[f*9+6], -(z*x));
            atomicAdd(&isum[f*9+7], -(z*y));
            atomicAdd(&isum[f*9+8], r2 - z*z);
        }
    } else {
        int j = (b - PREP_B5)*256 + t;
        if (j < N_PROT){
            float px = ppos[j*3+0], py = ppos[j*3+1], pz = ppos[j*3+2];
            float p2 = px*px + py*py + pz*pz;
            *(float4*)(ppos4 + (size_t)j*4) = make_float4(px, py, pz, p2);
        }
    }
}

// ---------------------------------------------------------------- KNN: single-level linear-d2 radix select (exact top-32)
__global__ __launch_bounds__(256) void k_knn(const float* __restrict__ apos,
                                             const float* __restrict__ ppos4,
                                             const int* __restrict__ abatch,
                                             const int* __restrict__ pstart,
                                             int* __restrict__ src_out){
    __shared__ int h1[256];
    __shared__ int s_info[4];
    __shared__ int s_nsel;
    __shared__ int s_nbound;
    __shared__ unsigned long long s_bound[512];

    const int i = blockIdx.x, t = threadIdx.x;
    const int lane = t & 63;
    const int b = abatch[i];
    const int p0 = pstart[b], p1 = pstart[b+1];
    const float ax = apos[i*3+0], ay = apos[i*3+1], az = apos[i*3+2];
    const float a2 = ax*ax + ay*ay + az*az;
    const float BINSCALE = 256.0f / 9.0f;
    const float4* pp4 = (const float4*)ppos4;

    unsigned kb[12];
    int jj[12];
    int bn[12];
#pragma unroll
    for (int q = 0; q < 12; ++q){
        int j = p0 + q*256 + t;
        unsigned kk = 0xFFFFFFFFu;
        int bin = -1;
        if (j < p1){
            float4 pp = pp4[j];
            float dt = ax*pp.x + ay*pp.y + az*pp.z;
            float d2 = fmaxf((a2 + pp.w) - 2.0f*dt, 0.f);
            if (d2 <= 9.0f){
                kk = __float_as_uint(d2);
                bin = (int)(d2 * BINSCALE);
                if (bin > 255) bin = 255;
            }
        }
        kb[q] = kk; jj[q] = j; bn[q] = bin;
    }
    h1[t] = 0;
    if (t == 0){ s_nsel = 0; s_nbound = 0; }
    __syncthreads();
#pragma unroll
    for (int q = 0; q < 12; ++q)
        if (bn[q] >= 0) atomicAdd(&h1[bn[q]], 1);
    __syncthreads();
    if (t < 64){
        int base = t*4;
        int a0 = h1[base], a1 = h1[base+1], a2i = h1[base+2], a3 = h1[base+3];
        int lsum = a0 + a1 + a2i + a3;
        int sc = lsum;
#pragma unroll
        for (int off = 1; off < 64; off <<= 1){
            int v = __shfl_up(sc, off);
            if (lane >= off) sc += v;
        }
        int ex = sc - lsum;
        h1[base]   = ex + a0;
        h1[base+1] = ex + a0 + a1;
        h1[base+2] = ex + a0 + a1 + a2i;
        h1[base+3] = sc;
        if (t == 63) s_info[3] = sc;
    }
    __syncthreads();
    const int total = s_info[3];
    const int kth = (total < KNN) ? total : KNN;
    if (kth > 0){
        int cum  = h1[t];
        int prev = (t == 0) ? 0 : h1[t-1];
        if (cum >= kth && prev < kth){ s_info[0] = t; }
    }
    __syncthreads();
    const int B = s_info[0];
    if (kth > 0){
#pragma unroll
        for (int q = 0; q < 12; ++q){
            if (bn[q] < 0) continue;
            if (bn[q] < B){
                int pos = atomicAdd(&s_nsel, 1);
                src_out[i*KNN + pos] = jj[q];
            } else if (bn[q] == B){
                int bi = atomicAdd(&s_nbound, 1);
                if (bi < 512) s_bound[bi] = ((unsigned long long)kb[q] << 32) | (unsigned)jj[q];
            }
        }
    }
    __syncthreads();
    const int base_n = s_nsel;
    const int R = kth - base_n;
    if (t < 64 && R > 0){
        int L = s_nbound; if (L > 512) L = 512;
        for (int r = 0; r < R; ++r){
            unsigned long long m = ~0ull;
            for (int idx = lane; idx < L; idx += 64) m = ullmin2(m, s_bound[idx]);
#pragma unroll
            for (int off = 32; off >= 1; off >>= 1)
                m = ullmin2(m, (unsigned long long)__shfl_xor((unsigned long long)m, off));
            if (lane == 0) src_out[i*KNN + base_n + r] = (int)(unsigned)(m & 0xFFFFFFFFull);
            for (int idx = lane; idx < L; idx += 64)
                if (s_bound[idx] == m) s_bound[idx] = ~0ull;
        }
    }
    if (t < KNN && t >= kth) src_out[i*KNN + t] = -1;
}

// ---------------------------------------------------------------- CSR prefix + frag centers (merged, 1 block x 1024)
__global__ __launch_bounds__(1024) void k_csr_prefix(const float* __restrict__ cnt,
                                                     const float* __restrict__ tsum,
                                                     const float* __restrict__ isum,
                                                     int* __restrict__ csr_off,
                                                     int* __restrict__ csr_cur,
                                                     float* __restrict__ tfrag,
                                                     float* __restrict__ ifin){
    __shared__ int s[1024];
    int t = threadIdx.x;
    float cn_raw = cnt[t];
    int v = (int)cn_raw;
    s[t] = v;
    {
        float cn = fmaxf(cn_raw, 1.f);
        tfrag[t*3+0] = tsum[t*3+0] / cn;
        tfrag[t*3+1] = tsum[t*3+1] / cn;
        tfrag[t*3+2] = tsum[t*3+2] / cn;
        float tr  = isum[t*9+0] + isum[t*9+4] + isum[t*9+8];
        float add = 1e-4f * fmaxf(tr, 1.f);
#pragma unroll
        for (int q = 0; q < 9; ++q){
            float vv = isum[t*9+q];
            if (q == 0 || q == 4 || q == 8) vv += add;
            ifin[t*9+q] = vv;
        }
    }
    __syncthreads();
    for (int off = 1; off < 1024; off <<= 1){
        int x = (t >= off) ? s[t-off] : 0;
        __syncthreads();
        s[t] += x;
        __syncthreads();
    }
    int incl = s[t];
    int excl = incl - v;
    csr_off[t] = excl;
    csr_cur[t] = excl;
    if (t == 1023) csr_off[1024] = incl;
}

__global__ void k_csr_scatter(const int* __restrict__ fid, int* __restrict__ csr_cur,
                              int* __restrict__ csr_atom){
    int a = blockIdx.x*256 + threadIdx.x;
    if (a >= N_ATOM) return;
    int f = fid[a];
    int pos = atomicAdd(&csr_cur[f], 1);
    csr_atom[pos] = a;
}

// ---------------------------------------------------------------- common[a][n] = b1[n] + [has|temb]_a . W1[144:400]
__global__ __launch_bounds__(256) void k_ctx(const float* __restrict__ has_,
                                             const float* __restrict__ temb,
                                             const short* __restrict__ W1cp,
                                             const float* __restrict__ b1,
                                             float* __restrict__ common){
    __shared__ __align__(16) char s_a[64*512];
    const int t = threadIdx.x, l = t & 63, w = t >> 6, g = l >> 4;
    const int a0 = blockIdx.x * 64;
    {
        int r = t & 63, seg = t >> 6;
        const float* srcp = (seg < 2) ? (has_ + (size_t)(a0 + r)*128 + seg*64)
                                      : (temb + (size_t)(a0 + r)*128 + (seg - 2)*64);
#pragma unroll
        for (int q = 0; q < 16; ++q){
            float4 x = *(const float4*)(srcp + q*4);
            int col = seg*64 + q*4;
            int off = (r*512 + col*2) ^ ((r & 7) << 4);
            *(unsigned*)(s_a + off)     = f2bf2(x.x, x.y);
            *(unsigned*)(s_a + off + 4) = f2bf2(x.z, x.w);
        }
    }
    __syncthreads();
    f32x4 acc[4][4];
#pragma unroll
    for (int mt = 0; mt < 4; ++mt)
#pragma unroll
        for (int nt = 0; nt < 4; ++nt) acc[mt][nt] = (f32x4){0.f,0.f,0.f,0.f};
    for (int ks = 0; ks < 8; ++ks){
        bf16x8 afr[4];
#pragma unroll
        for (int mt = 0; mt < 4; ++mt){
            int row = mt*16 + (l & 15);
            int off = (row*512 + ks*64 + g*16) ^ ((row & 7) << 4);
            afr[mt] = *(const bf16x8*)(s_a + off);
        }
#pragma unroll
        for (int nt = 0; nt < 4; ++nt){
            bf16x8 b = *(const bf16x8*)(W1cp + ((size_t)((ks*16 + (w*4 + nt))*64 + l))*8);
#pragma unroll
            for (int mt = 0; mt < 4; ++mt)
                acc[mt][nt] = __builtin_amdgcn_mfma_f32_16x16x32_bf16(afr[mt], b, acc[mt][nt], 0, 0, 0);
        }
    }
#pragma unroll
    for (int nt = 0; nt < 4; ++nt){
        int col = w*64 + nt*16 + (l & 15);
        float bb = b1[col];
#pragma unroll
        for (int mt = 0; mt < 4; ++mt)
#pragma unroll
            for (int r = 0; r < 4; ++r){
                int row = mt*16 + g*4 + r;
                common[(size_t)(a0 + row)*256 + col] = acc[mt][nt][r] + bb;
            }
    }
}

// ---------------------------------------------------------------- residue->atom conv (512 thr = 8 waves = 1 atom)
#define ES_STR 336   // bytes per es row (160 bf16 + 8 pad)
__global__ __launch_bounds__(512, 2) void k_ra3(
    const float* __restrict__ apos, const float* __restrict__ ppos,
    const short* __restrict__ hpsB, const short* __restrict__ hpvT,
    const short* __restrict__ W1p, const short* __restrict__ W2p,
    const short* __restrict__ Wsp, const short* __restrict__ Wvp,
    const float* __restrict__ common, const float* __restrict__ b2,
    const int* __restrict__ src,
    short* __restrict__ msR, short* __restrict__ mvR)
{
    __shared__ __align__(16) char s_es[32*ES_STR];
    __shared__ __align__(16) char s_h1[32*512];
    __shared__ __align__(16) char s_hpv[3*4096];
    __shared__ float s_unit[32][3];

    const int t = threadIdx.x;
    const int i = blockIdx.x;
    const int l = t & 63, w = t >> 6, g = l >> 4, r0 = l & 15;
    const int xm = (r0 & 7) << 4;
    float* s_mvA = (float*)s_es;
    float* s_mvB = s_mvA + 192;

    {
        const int e = t >> 4, sub = t & 15;
        const int j = src[i*KNN + e];
        float dx = 0.f, dy = 0.f, dz = 0.f, dist = 0.f;
        if (j >= 0){
            dx = apos[i*3+0] - ppos[j*3+0];
            dy = apos[i*3+1] - ppos[j*3+1];
            dz = apos[i*3+2] - ppos[j*3+2];
            dist = sqrtf(dx*dx + dy*dy + dz*dz);
        }
        if (sub == 0){
            float inv = 1.f / (dist + 1e-8f);
            s_unit[e][0] = dx*inv; s_unit[e][1] = dy*inv; s_unit[e][2] = dz*inv;
        }
        if (sub < 2){
            const float gamma = 16.0f / 6.0f;
#pragma unroll
            for (int q = 0; q < 4; ++q){
                int kk = sub*8 + q*2;
                float mu0  = 0.4f * (float)kk;
                float mu1  = 0.4f * (float)(kk+1);
                float a0 = gamma * (dist - mu0);
                float a1 = gamma * (dist - mu1);
                float e0 = (j >= 0) ? __expf(-(a0*a0)) : 0.f;
                float e1 = (j >= 0) ? __expf(-(a1*a1)) : 0.f;
                *(unsigned*)(s_es + e*ES_STR + kk*2) = f2bf2(e0, e1);
            }
        }
        if (sub < 8) *(int*)(s_es + e*ES_STR + 288 + sub*4) = 0;
        const bf16x8 zv = (bf16x8){0,0,0,0,0,0,0,0};
        {
            bf16x8 hc = (j >= 0) ? *(const bf16x8*)(hpsB + (size_t)j*128 + sub*8) : zv;
            *(bf16x8*)(s_es + e*ES_STR + 32 + sub*16) = hc;
        }
        const int em = (e & 7) << 4;
        {
            bf16x8 c0 = (j >= 0) ? *(const bf16x8*)(hpvT + (size_t)j*192 + sub*8) : zv;
            *(bf16x8*)(s_hpv + (sub>>3)*4096 + e*128 + (((sub&7)<<4) ^ em)) = c0;
            if (sub < 8){
                bf16x8 c1 = (j >= 0) ? *(const bf16x8*)(hpvT + (size_t)j*192 + (16+sub)*8) : zv;
                *(bf16x8*)(s_hpv + 2*4096 + e*128 + ((sub<<4) ^ em)) = c1;
            }
        }
    }
    __syncthreads();

    f32x4 acc1[2][2];
#pragma unroll
    for (int mt = 0; mt < 2; ++mt)
#pragma unroll
        for (int nt = 0; nt < 2; ++nt) acc1[mt][nt] = (f32x4){0.f,0.f,0.f,0.f};
    for (int ks = 0; ks < 5; ++ks){
        bf16x8 a0 = *(const bf16x8*)(s_es + r0*ES_STR + ks*64 + g*16);
        bf16x8 a1 = *(const bf16x8*)(s_es + (16 + r0)*ES_STR + ks*64 + g*16);
#pragma unroll
        for (int nt = 0; nt < 2; ++nt){
            bf16x8 b = *(const bf16x8*)(W1p + ((size_t)((ks*16 + (w*2 + nt))*64 + l))*8);
            acc1[0][nt] = __builtin_amdgcn_mfma_f32_16x16x32_bf16(a0, b, acc1[0][nt], 0, 0, 0);
            acc1[1][nt] = __builtin_amdgcn_mfma_f32_16x16x32_bf16(a1, b, acc1[1][nt], 0, 0, 0);
        }
    }

#pragma unroll
    for (int nt = 0; nt < 2; ++nt){
        int col = w*32 + nt*16 + r0;
        float cm = common[(size_t)i*256 + col];
#pragma unroll
        for (int mt = 0; mt < 2; ++mt)
#pragma unroll
            for (int r = 0; r < 4; ++r){
                float v = silu_f(acc1[mt][nt][r] + cm);
                int row = mt*16 + g*4 + r;
                int off = (row*512 + col*2) ^ ((row & 7) << 4);
                *(short*)(s_h1 + off) = f2bf(v);
            }
    }

    f32x4 accxs[2][2];
#pragma unroll
    for (int mt = 0; mt < 2; ++mt)
#pragma unroll
        for (int nt = 0; nt < 2; ++nt) accxs[mt][nt] = (f32x4){0.f,0.f,0.f,0.f};
    if (w < 4){
        for (int ks = 0; ks < 4; ++ks){
            bf16x8 a0 = *(const bf16x8*)(s_es + r0*ES_STR + 32 + ks*64 + g*16);
            bf16x8 a1 = *(const bf16x8*)(s_es + (16 + r0)*ES_STR + 32 + ks*64 + g*16);
#pragma unroll
            for (int nt = 0; nt < 2; ++nt){
                bf16x8 b = *(const bf16x8*)(Wsp + ((size_t)((ks*8 + (w*2 + nt))*64 + l))*8);
                accxs[0][nt] = __builtin_amdgcn_mfma_f32_16x16x32_bf16(a0, b, accxs[0][nt], 0, 0, 0);
                accxs[1][nt] = __builtin_amdgcn_mfma_f32_16x16x32_bf16(a1, b, accxs[1][nt], 0, 0, 0);
            }
        }
    }
    __syncthreads();

    f32x4 accw[2][2];
#pragma unroll
    for (int mt = 0; mt < 2; ++mt)
#pragma unroll
        for (int nt = 0; nt < 2; ++nt) accw[mt][nt] = (f32x4){0.f,0.f,0.f,0.f};
    for (int ks = 0; ks < 8; ++ks){
        int off0 = (r0*512 + ks*64 + g*16) ^ xm;
        bf16x8 a0 = *(const bf16x8*)(s_h1 + off0);
        bf16x8 a1 = *(const bf16x8*)(s_h1 + off0 + 8192);
#pragma unroll
        for (int nt = 0; nt < 2; ++nt){
            bf16x8 b = *(const bf16x8*)(W2p + ((size_t)((ks*16 + (w*2 + nt))*64 + l))*8);
            accw[0][nt] = __builtin_amdgcn_mfma_f32_16x16x32_bf16(a0, b, accw[0][nt], 0, 0, 0);
            accw[1][nt] = __builtin_amdgcn_mfma_f32_16x16x32_bf16(a1, b, accw[1][nt], 0, 0, 0);
        }
    }
    float b2v[2];
#pragma unroll
    for (int nt = 0; nt < 2; ++nt) b2v[nt] = b2[w*32 + nt*16 + r0];

    if (w < 4){
#pragma unroll
        for (int nt = 0; nt < 2; ++nt){
            float p = 0.f;
#pragma unroll
            for (int mt = 0; mt < 2; ++mt)
#pragma unroll
                for (int r = 0; r < 4; ++r)
                    p = fmaf(accw[mt][nt][r] + b2v[nt], accxs[mt][nt][r], p);
            p += __shfl_xor(p, 16);
            p += __shfl_xor(p, 32);
            if (l < 16) msR[(size_t)i*128 + w*32 + nt*16 + r0] = f2bf(p);
        }
    } else if (w < 6){
        bf16x8 bv[2][2];
#pragma unroll
        for (int ks = 0; ks < 2; ++ks)
#pragma unroll
            for (int nt = 0; nt < 2; ++nt)
                bv[ks][nt] = *(const bf16x8*)(Wvp + ((size_t)((ks*4 + (w-4)*2 + nt)*64 + l))*8);
#pragma unroll
        for (int c = 0; c < 3; ++c){
            f32x4 accxv[2][2];
#pragma unroll
            for (int mt = 0; mt < 2; ++mt)
#pragma unroll
                for (int nt = 0; nt < 2; ++nt) accxv[mt][nt] = (f32x4){0.f,0.f,0.f,0.f};
#pragma unroll
            for (int ks = 0; ks < 2; ++ks){
                int off0 = c*4096 + r0*128 + ((ks*64 + g*16) ^ xm);
                bf16x8 a0 = *(const bf16x8*)(s_hpv + off0);
                bf16x8 a1 = *(const bf16x8*)(s_hpv + off0 + 2048);
#pragma unroll
                for (int nt = 0; nt < 2; ++nt){
                    accxv[0][nt] = __builtin_amdgcn_mfma_f32_16x16x32_bf16(a0, bv[ks][nt], accxv[0][nt], 0, 0, 0);
                    accxv[1][nt] = __builtin_amdgcn_mfma_f32_16x16x32_bf16(a1, bv[ks][nt], accxv[1][nt], 0, 0, 0);
                }
            }
#pragma unroll
            for (int nt = 0; nt < 2; ++nt){
                float p = 0.f;
#pragma unroll
                for (int mt = 0; mt < 2; ++mt)
#pragma unroll
                    for (int r = 0; r < 4; ++r)
                        p = fmaf(accw[mt][nt][r] + b2v[nt], accxv[mt][nt][r], p);
                p += __shfl_xor(p, 16);
                p += __shfl_xor(p, 32);
                if (l < 16) s_mvA[c*64 + (w-4)*32 + nt*16 + r0] = p;
            }
        }
    } else {
        float uu[8][3];
#pragma unroll
        for (int mt = 0; mt < 2; ++mt)
#pragma unroll
            for (int r = 0; r < 4; ++r){
                int e = mt*16 + g*4 + r;
#pragma unroll
                for (int c = 0; c < 3; ++c) uu[mt*4+r][c] = s_unit[e][c];
            }
#pragma unroll
        for (int c = 0; c < 3; ++c)
#pragma unroll
            for (int nt = 0; nt < 2; ++nt){
                float p = 0.f;
#pragma unroll
                for (int mt = 0; mt < 2; ++mt)
#pragma unroll
                    for (int r = 0; r < 4; ++r)
                        p = fmaf(accw[mt][nt][r] + b2v[nt], uu[mt*4+r][c], p);
                p += __shfl_xor(p, 16);
                p += __shfl_xor(p, 32);
                if (l < 16) s_mvB[c*64 + (w-6)*32 + nt*16 + r0] = p;
            }
    }
    __syncthreads();

    if (t < 192){
        int wi = t & 63, cc = t >> 6;
        float v = s_mvA[cc*64 + wi] + s_mvB[cc*64 + wi];
        mvR[((size_t)i*3 + cc)*64 + wi] = f2bf(v);
    }
}

// ---------------------------------------------------------------- batched output transforms (MFMA) + bf16 dual-write
__global__ __launch_bounds__(256) void k_ra_out(
    const short* __restrict__ msR, const short* __restrict__ mvR,
    const short* __restrict__ Wosp, const short* __restrict__ Wovp,
    const float* __restrict__ has_, const float* __restrict__ hav,
    float* __restrict__ out,
    short* __restrict__ haB, short* __restrict__ havT)
{
    const int t = threadIdx.x, l = t & 63, w = t >> 6, g = l >> 4, r0 = l & 15;
    const int a0 = blockIdx.x * 32;

    f32x4 acc[2][2];
#pragma unroll
    for (int mt = 0; mt < 2; ++mt)
#pragma unroll
        for (int nt = 0; nt < 2; ++nt) acc[mt][nt] = (f32x4){0.f,0.f,0.f,0.f};
    for (int ks = 0; ks < 4; ++ks){
        bf16x8 af0 = *(const bf16x8*)(msR + ((size_t)(a0 + r0)*128 + ks*32 + g*8));
        bf16x8 af1 = *(const bf16x8*)(msR + ((size_t)(a0 + 16 + r0)*128 + ks*32 + g*8));
#pragma unroll
        for (int nt = 0; nt < 2; ++nt){
            bf16x8 b = *(const bf16x8*)(Wosp + ((size_t)((ks*8 + (w*2 + nt))*64 + l))*8);
            acc[0][nt] = __builtin_amdgcn_mfma_f32_16x16x32_bf16(af0, b, acc[0][nt], 0, 0, 0);
            acc[1][nt] = __builtin_amdgcn_mfma_f32_16x16x32_bf16(af1, b, acc[1][nt], 0, 0, 0);
        }
    }
#pragma unroll
    for (int nt = 0; nt < 2; ++nt){
        int col = w*32 + nt*16 + r0;
#pragma unroll
        for (int mt = 0; mt < 2; ++mt)
#pragma unroll
            for (int r = 0; r < 4; ++r){
                int a = a0 + mt*16 + g*4 + r;
                float val = has_[(size_t)a*128 + col] + silu_f(acc[mt][nt][r]);
                out[(size_t)a*OUTC + col] = val;
                haB[(size_t)a*128 + col] = f2bf(val);
            }
    }

    f32x4 accv[6];
#pragma unroll
    for (int mt = 0; mt < 6; ++mt) accv[mt] = (f32x4){0.f,0.f,0.f,0.f};
    for (int ks = 0; ks < 2; ++ks){
        bf16x8 b = *(const bf16x8*)(Wovp + ((size_t)((ks*4 + w)*64 + l))*8);
#pragma unroll
        for (int mt = 0; mt < 6; ++mt){
            bf16x8 af = *(const bf16x8*)(mvR + ((size_t)(a0*3 + mt*16 + r0)*64 + ks*32 + g*8));
            accv[mt] = __builtin_amdgcn_mfma_f32_16x16x32_bf16(af, b, accv[mt], 0, 0, 0);
        }
    }
    const int wi = w*16 + r0;
#pragma unroll
    for (int mt = 0; mt < 6; ++mt)
#pragma unroll
        for (int r = 0; r < 4; ++r){
            int R = mt*16 + g*4 + r;
            int a = a0 + R/3, c = R - (R/3)*3;
            float val = hav[(size_t)a*192 + wi*3 + c] + accv[mt][r];
            out[(size_t)a*OUTC + 128 + wi*3 + c] = val;
            havT[(size_t)a*192 + c*64 + wi] = f2bf(val);
        }
}

// ---------------------------------------------------------------- atom->frag conv, MFMA (1 block = 16 atoms, 2 blk/CU)
#define AES_STR 848  // bytes per es row (416 bf16 + 8 pad)
__global__ __launch_bounds__(256, 2) void k_af2(
    const float* __restrict__ apos, const float* __restrict__ tfrag,
    const short* __restrict__ haB, const short* __restrict__ hfsB,
    const short* __restrict__ tembB, const short* __restrict__ havT,
    const short* __restrict__ W1p, const float* __restrict__ b1,
    const short* __restrict__ W2p, const float* __restrict__ b2,
    const short* __restrict__ Wsp, const short* __restrict__ Wvp,
    const int* __restrict__ fragid,
    short* __restrict__ msA, short* __restrict__ mvA)
{
    __shared__ __align__(16) char s_es[16*AES_STR];
    __shared__ __align__(16) char s_h1[16*512];
    __shared__ __align__(16) char s_pv[3*2048];
    __shared__ float s_unit[16][3];
    float* s_upr = (float*)s_es;

    const int t = threadIdx.x, a0 = blockIdx.x*16;
    const int l = t & 63, w = t >> 6, g = l >> 4, r0 = l & 15;
    const int xm = (r0 & 7) << 4;

    {
        const int e = t >> 4, sub = t & 15;
        const int a = a0 + e;
        const int f = fragid[a];
        float rx = apos[a*3+0] - tfrag[f*3+0];
        float ry = apos[a*3+1] - tfrag[f*3+1];
        float rz = apos[a*3+2] - tfrag[f*3+2];
        float dist = sqrtf(rx*rx + ry*ry + rz*rz);
        if (sub == 0){
            float inv = 1.f / (dist + 1e-8f);
            s_unit[e][0] = rx*inv; s_unit[e][1] = ry*inv; s_unit[e][2] = rz*inv;
        }
        if (sub < 2){
            const float gamma = 16.0f / 6.0f;
#pragma unroll
            for (int q = 0; q < 4; ++q){
                int kk = sub*8 + q*2;
                float mu0  = 0.4f * (float)kk;
                float mu1  = 0.4f * (float)(kk+1);
                float a0f = gamma * (dist - mu0);
                float a1f = gamma * (dist - mu1);
                *(unsigned*)(s_es + e*AES_STR + kk*2) = f2bf2(__expf(-(a0f*a0f)), __expf(-(a1f*a1f)));
            }
        }
        *(bf16x8*)(s_es + e*AES_STR + 32  + sub*16) = *(const bf16x8*)(haB  + (size_t)a*128 + sub*8);
        *(bf16x8*)(s_es + e*AES_STR + 288 + sub*16) = *(const bf16x8*)(hfsB + (size_t)f*128 + sub*8);
        *(bf16x8*)(s_es + e*AES_STR + 544 + sub*16) = *(const bf16x8*)(tembB + (size_t)a*128 + sub*8);
        *(short*)(s_es + e*AES_STR + 800 + sub*2) = 0;
        const int em = (e & 7) << 4;
        {
            bf16x8 c0 = *(const bf16x8*)(havT + (size_t)a*192 + sub*8);
            *(bf16x8*)(s_pv + (sub>>3)*2048 + e*128 + (((sub&7)<<4) ^ em)) = c0;
            if (sub < 8){
                bf16x8 c1 = *(const bf16x8*)(havT + (size_t)a*192 + (16+sub)*8);
                *(bf16x8*)(s_pv + 2*2048 + e*128 + ((sub<<4) ^ em)) = c1;
            }
        }
    }
    __syncthreads();

    f32x4 acc1[4];
#pragma unroll
    for (int nt = 0; nt < 4; ++nt) acc1[nt] = (f32x4){0.f,0.f,0.f,0.f};
    for (int ks = 0; ks < 13; ++ks){
        bf16x8 a0f = *(const bf16x8*)(s_es + r0*AES_STR + ks*64 + g*16);
#pragma unroll
        for (int nt = 0; nt < 4; ++nt){
            bf16x8 b = *(const bf16x8*)(W1p + ((size_t)((ks*16 + (w*4 + nt))*64 + l))*8);
            acc1[nt] = __builtin_amdgcn_mfma_f32_16x16x32_bf16(a0f, b, acc1[nt], 0, 0, 0);
        }
    }
#pragma unroll
    for (int nt = 0; nt < 4; ++nt){
        int col = w*64 + nt*16 + r0;
        float bb = b1[col];
#pragma unroll
        for (int r = 0; r < 4; ++r){
            float v = silu_f(acc1[nt][r] + bb);
            int row = g*4 + r;
            int off = (row*512 + col*2) ^ ((row & 7) << 4);
            *(short*)(s_h1 + off) = f2bf(v);
        }
    }
    f32x4 accxs[4];
#pragma unroll
    for (int nt = 0; nt < 4; ++nt) accxs[nt] = (f32x4){0.f,0.f,0.f,0.f};
    if (w < 2){
        for (int ks = 0; ks < 4; ++ks){
            bf16x8 a0f = *(const bf16x8*)(s_es + r0*AES_STR + 32 + ks*64 + g*16);
#pragma unroll
            for (int nt = 0; nt < 4; ++nt){
                bf16x8 b = *(const bf16x8*)(Wsp + ((size_t)((ks*8 + (w*4 + nt))*64 + l))*8);
                accxs[nt] = __builtin_amdgcn_mfma_f32_16x16x32_bf16(a0f, b, accxs[nt], 0, 0, 0);
            }
        }
    }
    __syncthreads();

    f32x4 accw[4];
#pragma unroll
    for (int nt = 0; nt < 4; ++nt) accw[nt] = (f32x4){0.f,0.f,0.f,0.f};
    for (int ks = 0; ks < 8; ++ks){
        int off0 = (r0*512 + ks*64 + g*16) ^ xm;
        bf16x8 a0f = *(const bf16x8*)(s_h1 + off0);
#pragma unroll
        for (int nt = 0; nt < 4; ++nt){
            bf16x8 b = *(const bf16x8*)(W2p + ((size_t)((ks*16 + (w*4 + nt))*64 + l))*8);
            accw[nt] = __builtin_amdgcn_mfma_f32_16x16x32_bf16(a0f, b, accw[nt], 0, 0, 0);
        }
    }
    float b2v[4];
#pragma unroll
    for (int nt = 0; nt < 4; ++nt) b2v[nt] = b2[w*64 + nt*16 + r0];

    if (w == 3){
        float uu[4][3];
#pragma unroll
        for (int r = 0; r < 4; ++r){
            int e = g*4 + r;
#pragma unroll
            for (int c = 0; c < 3; ++c) uu[r][c] = s_unit[e][c];
        }
#pragma unroll
        for (int nt = 0; nt < 4; ++nt){
            int wi = nt*16 + r0;
#pragma unroll
            for (int r = 0; r < 4; ++r){
                int e = g*4 + r;
                float gate = accw[nt][r] + b2v[nt];
#pragma unroll
                for (int c = 0; c < 3; ++c)
                    s_upr[e*192 + wi*3 + c] = gate * uu[r][c];
            }
        }
    }
    __syncthreads();

    if (w < 2){
#pragma unroll
        for (int nt = 0; nt < 4; ++nt){
            int col = w*64 + nt*16 + r0;
#pragma unroll
            for (int r = 0; r < 4; ++r){
                int e = g*4 + r;
                float p = (accw[nt][r] + b2v[nt]) * accxs[nt][r];
                msA[(size_t)(a0 + e)*128 + col] = f2bf(p);
            }
        }
    } else if (w == 2){
        bf16x8 bv[2][4];
#pragma unroll
        for (int ks = 0; ks < 2; ++ks)
#pragma unroll
            for (int nt = 0; nt < 4; ++nt)
                bv[ks][nt] = *(const bf16x8*)(Wvp + ((size_t)((ks*4 + nt)*64 + l))*8);
#pragma unroll
        for (int c = 0; c < 3; ++c){
            f32x4 accxv[4];
#pragma unroll
            for (int nt = 0; nt < 4; ++nt) accxv[nt] = (f32x4){0.f,0.f,0.f,0.f};
#pragma unroll
            for (int ks = 0; ks < 2; ++ks){
                int off0 = c*2048 + r0*128 + ((ks*64 + g*16) ^ xm);
                bf16x8 a0f = *(const bf16x8*)(s_pv + off0);
#pragma unroll
                for (int nt = 0; nt < 4; ++nt)
                    accxv[nt] = __builtin_amdgcn_mfma_f32_16x16x32_bf16(a0f, bv[ks][nt], accxv[nt], 0, 0, 0);
            }
#pragma unroll
            for (int nt = 0; nt < 4; ++nt){
                int wi = nt*16 + r0;
#pragma unroll
                for (int r = 0; r < 4; ++r){
                    int e = g*4 + r;
                    float p = (accw[nt][r] + b2v[nt]) * accxv[nt][r]
                            + s_upr[e*192 + wi*3 + c];
                    mvA[(size_t)(a0 + e)*192 + wi*3 + c] = f2bf(p);
                }
            }
        }
    }
}

// ---------------------------------------------------------------- frag update (CSR gather + transform + direct scatter)
__global__ __launch_bounds__(256) void k_fragupd(
    const int* __restrict__ csr_off, const int* __restrict__ csr_atom,
    const short* __restrict__ msA, const short* __restrict__ mvA,
    const float* __restrict__ hfs_in, const float* __restrict__ hfv_in,
    const float* __restrict__ Wfs, const float* __restrict__ Wfv,
    const float* __restrict__ ifin,
    float* __restrict__ out)
{
    __shared__ __align__(16) float s_fs[128];
    __shared__ __align__(16) float s_fv[192];
    const int f = blockIdx.x, t = threadIdx.x;
    const int n0 = csr_off[f], n1 = csr_off[f+1];
    if (t < 128){
        float s = 0.f;
        for (int n = n0; n < n1; ++n){
            int a = csr_atom[n];
            s += bf2f(msA[(size_t)a*128 + t]);
        }
        s_fs[t] = s;
    }
    if (t >= 64){
        int idx = t - 64;
        float s = 0.f;
        for (int n = n0; n < n1; ++n){
            int a = csr_atom[n];
            s += bf2f(mvA[(size_t)a*192 + idx]);
        }
        s_fv[(idx % 3)*64 + (idx / 3)] = s;
    }
    __syncthreads();
    if (t < 128){
        float o = 0.f;
        for (int k = 0; k < 128; k += 4){
            const float* wr = &Wfs[k*128 + t];
            float4 m4 = *(const float4*)&s_fs[k];
            o = fmaf(m4.x, wr[0],   o);
            o = fmaf(m4.y, wr[128], o);
            o = fmaf(m4.z, wr[256], o);
            o = fmaf(m4.w, wr[384], o);
        }
        float val = hfs_in[f*128 + t] + silu_f(o);
        for (int n = n0; n < n1; ++n)
            out[(size_t)csr_atom[n]*OUTC + 320 + t] = val;
    }
    if (t < 192){
        const int wi = t & 63, cc = t >> 6;
        float o = 0.f;
        for (int v = 0; v < 64; v += 4){
            const float* wr = &Wfv[v*64 + wi];
            float4 m4 = *(const float4*)&s_fv[cc*64 + v];
            o = fmaf(m4.x, wr[0],   o);
            o = fmaf(m4.y, wr[64],  o);
            o = fmaf(m4.z, wr[128], o);
            o = fmaf(m4.w, wr[192], o);
        }
        float val = hfv_in[f*192 + wi*3 + cc] + o;
        for (int n = n0; n < n1; ++n)
            out[(size_t)csr_atom[n]*OUTC + 448 + wi*3 + cc] = val;
    } else if (t < 201){
        int q = t - 192;
        float val = ifin[f*9 + q];
        for (int n = n0; n < n1; ++n)
            out[(size_t)csr_atom[n]*OUTC + 640 + q] = val;
    }
}

// ----------------------------------------------------------------
extern "C" void kernel_launch(void* const* d_in, const int* in_sizes, int n_in,
                              void* d_out, int out_size, void* d_ws, size_t ws_size,
                              hipStream_t stream)
{
    const float* atom_pos   = (const float*)d_in[0];
    const float* prot_pos   = (const float*)d_in[1];
    const float* local_pos  = (const float*)d_in[2];
    const float* h_atom_s   = (const float*)d_in[3];
    const float* h_atom_v   = (const float*)d_in[4];
    const float* h_prot_s   = (const float*)d_in[5];
    const float* h_prot_v   = (const float*)d_in[6];
    const float* h_frag_s   = (const float*)d_in[7];
    const float* h_frag_v   = (const float*)d_in[8];
    const float* t_emb      = (const float*)d_in[9];
    const float* W1_ra = (const float*)d_in[10]; const float* b1_ra = (const float*)d_in[11];
    const float* W2_ra = (const float*)d_in[12]; const float* b2_ra = (const float*)d_in[13];
    const float* Ws_ra = (const float*)d_in[14]; const float* Wv_ra = (const float*)d_in[15];
    const float* W1_af = (const float*)d_in[16]; const float* b1_af = (const float*)d_in[17];
    const float* W2_af = (const float*)d_in[18]; const float* b2_af = (const float*)d_in[19];
    const float* Ws_af = (const float*)d_in[20]; const float* Wv_af = (const float*)d_in[21];
    const float* Wo_s  = (const float*)d_in[22]; const float* Wo_v  = (const float*)d_in[23];
    const float* Wf_s  = (const float*)d_in[24]; const float* Wf_v  = (const float*)d_in[25];
    const int* fragment_id = (const int*)d_in[26];
    const int* atom_batch  = (const int*)d_in[27];
    const int* prot_batch  = (const int*)d_in[28];
    float* out = (float*)d_out;

    // ---- workspace layout ----
    float* cnt   = (float*)d_ws;                 // 1024   (zeroed)
    float* tsum  = cnt  + 1024;                  // 3072   (zeroed)
    float* isum  = tsum + 3072;                  // 9216   (zeroed)
    float* tfrag = isum + 9216;                  // 3072
    float* ifin  = tfrag + 3072;                 // 9216
    float* hfs   = ifin + 9216;                  // 131072 (unused, layout stability)
    float* hfv   = hfs  + 1024*128;              // 196608 (unused)
    int*   pstart   = (int*)(hfv + 1024*192);    // 16
    int*   src      = pstart + 16;               // 262144
    int*   csr_off  = src + N_ATOM*KNN;          // 1025
    int*   csr_cur  = csr_off + 1025;            // 1024
    int*   csr_atom = csr_cur + 1024;            // 8192
    uintptr_t pal = ((uintptr_t)(csr_atom + 8192) + 127) & ~(uintptr_t)127;
    float* common = (float*)pal;                 // 8192*256 f32 (8 MB)
    // aliases inside common (dead after k_ra3):
    short* msA  = (short*)common;                // 2 MB  (written k_af2)
    short* mvA  = msA + (size_t)8192*128;        // 3 MB  (written k_af2)
    short* havT = mvA + (size_t)8192*192;        // 3 MB  (written k_ra_out)
    short* W1p  = (short*)(common + (size_t)8192*256);
    short* W2p  = W1p  + 40960;
    short* Wsp  = W2p  + 65536;
    short* Wvp  = Wsp  + 16384;
    short* W1cp = Wvp  + 4096;
    short* W1ap = W1cp + 65536;
    short* W2ap = W1ap + 106496;
    short* Wsap = W2ap + 65536;
    short* Wvap = Wsap + 16384;
    short* Wosp = Wvap + 4096;
    short* Wovp = Wosp + 16384;
    short* msR  = Wovp + 4096;                   // 8192*128 bf16 (2 MB)
    short* mvR  = msR + (size_t)8192*128;        // 8192*192 bf16 (3 MB)
    short* hpsB = mvR + (size_t)8192*192;        // 16384*128 bf16 (4 MB)
    short* hpvT = hpsB + (size_t)N_PROT*128;     // 16384*192 bf16 (6 MB)
    short* haB  = hpvT + (size_t)N_PROT*192;     // 8192*128 bf16 (2 MB)
    short* hfsB = haB + (size_t)8192*128;        // 1024*128 bf16 (256 KB)
    short* tembB= hfsB + (size_t)1024*128;       // 8192*128 bf16 (2 MB)
    uintptr_t p4 = ((uintptr_t)(tembB + (size_t)8192*128) + 15) & ~(uintptr_t)15;
    float* ppos4 = (float*)p4;                   // 16384*4 f32 (256 KB)

    size_t zero_bytes = (size_t)(1024 + 3072 + 9216) * sizeof(float);
    hipMemsetAsync(cnt, 0, zero_bytes, stream);

    k_prep    <<<PREP_NB, 256, 0, stream>>>(W1_ra, W2_ra, Ws_ra, Wv_ra, W1_af, W2_af, Ws_af, Wv_af,
                                            Wo_s, Wo_v,
                                            h_prot_s, h_prot_v, h_frag_s, t_emb,
                                            atom_pos, local_pos, prot_pos,
                                            fragment_id, prot_batch,
                                            W1p, W2p, Wsp, Wvp, W1cp, W1ap, W2ap, Wsap, Wvap,
                                            Wosp, Wovp,
                                            hpsB, hpvT, hfsB, tembB, ppos4, pstart,
                                            cnt, tsum, isum);
    k_knn     <<<N_ATOM, 256, 0, stream>>>(atom_pos, ppos4, atom_batch, pstart, src);
    k_ctx     <<<N_ATOM/64, 256, 0, stream>>>(h_atom_s, t_emb, W1cp, b1_ra, common);
    k_csr_prefix<<<1, 1024, 0, stream>>>(cnt, tsum, isum, csr_off, csr_cur, tfrag, ifin);
    k_csr_scatter<<<N_ATOM/256, 256, 0, stream>>>(fragment_id, csr_cur, csr_atom);
    k_ra3     <<<N_ATOM, 512, 0, stream>>>(atom_pos, prot_pos, hpsB, hpvT,
                                           W1p, W2p, Wsp, Wvp, common, b2_ra,
                                           src, msR, mvR);
    k_ra_out  <<<N_ATOM/32, 256, 0, stream>>>(msR, mvR, Wosp, Wovp, h_atom_s, h_atom_v, out,
                                              haB, havT);
    k_af2     <<<N_ATOM/16, 256, 0, stream>>>(atom_pos, tfrag, haB, hfsB, tembB, havT,
                                              W1ap, b1_af, W2ap, b2_af, Wsap, Wvap,
                                              fragment_id, msA, mvA);
    k_fragupd <<<N_FRAG, 256, 0, stream>>>(csr_off, csr_atom, msA, mvA,
                                           h_frag_s, h_frag_v, Wf_s, Wf_v, ifin, out);
}

// Round 24
// 230.818 us; speedup vs baseline: 1.0182x; 1.0013x over previous
//
#include <hip/hip_runtime.h>
#include <hip/hip_bf16.h>

#define N_ATOM 8192
#define N_PROT 16384
#define N_FRAG 1024
#define KNN    32
#define OUTC   649   // 128 + 192 + 128 + 192 + 9

typedef __attribute__((ext_vector_type(8))) short bf16x8;
typedef __attribute__((ext_vector_type(4))) float f32x4;

__device__ __forceinline__ float silu_f(float x){ return x / (1.f + __expf(-x)); }
__device__ __forceinline__ unsigned long long ullmin2(unsigned long long a, unsigned long long b){ return a < b ? a : b; }

__device__ __forceinline__ short f2bf(float x){
    __hip_bfloat16 h = __float2bfloat16(x);
    return *reinterpret_cast<short*>(&h);
}
// packed pair: 2 f32 -> 2 bf16 in one u32
__device__ __forceinline__ unsigned f2bf2(float lo, float hi){
    __hip_bfloat162 h2;
    h2.x = __float2bfloat16(lo);
    h2.y = __float2bfloat16(hi);
    return *reinterpret_cast<unsigned*>(&h2);
}
__device__ __forceinline__ float bf2f(short s){
    return __uint_as_float(((unsigned)(unsigned short)s) << 16);
}

// ================================================================ prep device parts (all elementwise, no LDS)
// pack id ranges (total 50688)
__device__ void dev_pack(int id,
                         const float* __restrict__ W1, const float* __restrict__ W2,
                         const float* __restrict__ Ws, const float* __restrict__ Wv,
                         const float* __restrict__ W1a, const float* __restrict__ W2a,
                         const float* __restrict__ Wsa, const float* __restrict__ Wva,
                         const float* __restrict__ Wos, const float* __restrict__ Wov,
                         short* __restrict__ W1p, short* __restrict__ W2p,
                         short* __restrict__ Wsp, short* __restrict__ Wvp,
                         short* __restrict__ W1cp,
                         short* __restrict__ W1ap, short* __restrict__ W2ap,
                         short* __restrict__ Wsap, short* __restrict__ Wvap,
                         short* __restrict__ Wosp, short* __restrict__ Wovp){
    if (id < 5120){
        int kt = id/1024, rem = id%1024, nt = rem/64, l = rem%64;
#pragma unroll
        for (int jj = 0; jj < 8; ++jj){
            int k = kt*32 + ((l>>4)<<3) + jj, n = nt*16 + (l&15);
            W1p[(size_t)id*8 + jj] = (k < 144) ? f2bf(W1[(size_t)k*256 + n]) : (short)0;
        }
    } else if (id < 13312){
        int id2 = id - 5120;
        int kt = id2/1024, rem = id2%1024, nt = rem/64, l = rem%64;
#pragma unroll
        for (int jj = 0; jj < 8; ++jj){
            int k = kt*32 + ((l>>4)<<3) + jj, n = nt*16 + (l&15);
            W2p[(size_t)id2*8 + jj] = f2bf(W2[(size_t)k*256 + n]);
        }
    } else if (id < 15360){
        int id2 = id - 13312;
        int kt = id2/512, rem = id2%512, nt = rem/64, l = rem%64;
#pragma unroll
        for (int jj = 0; jj < 8; ++jj){
            int k = kt*32 + ((l>>4)<<3) + jj, n = nt*16 + (l&15);
            Wsp[(size_t)id2*8 + jj] = f2bf(Ws[(size_t)k*128 + n]);
        }
    } else if (id < 15872){
        int id2 = id - 15360;
        int kt = id2/256, rem = id2%256, nt = rem/64, l = rem%64;
#pragma unroll
        for (int jj = 0; jj < 8; ++jj){
            int k = kt*32 + ((l>>4)<<3) + jj, n = nt*16 + (l&15);
            Wvp[(size_t)id2*8 + jj] = f2bf(Wv[(size_t)k*64 + n]);
        }
    } else if (id < 24064){
        int id2 = id - 15872;
        int kt = id2/1024, rem = id2%1024, nt = rem/64, l = rem%64;
#pragma unroll
        for (int jj = 0; jj < 8; ++jj){
            int k = kt*32 + ((l>>4)<<3) + jj, n = nt*16 + (l&15);
            W1cp[(size_t)id2*8 + jj] = f2bf(W1[(size_t)(144 + k)*256 + n]);
        }
    } else if (id < 37376){
        int id2 = id - 24064;
        int kt = id2/1024, rem = id2%1024, nt = rem/64, l = rem%64;
#pragma unroll
        for (int jj = 0; jj < 8; ++jj){
            int k = kt*32 + ((l>>4)<<3) + jj, n = nt*16 + (l&15);
            W1ap[(size_t)id2*8 + jj] = (k < 400) ? f2bf(W1a[(size_t)k*256 + n]) : (short)0;
        }
    } else if (id < 45568){
        int id2 = id - 37376;
        int kt = id2/1024, rem = id2%1024, nt = rem/64, l = rem%64;
#pragma unroll
        for (int jj = 0; jj < 8; ++jj){
            int k = kt*32 + ((l>>4)<<3) + jj, n = nt*16 + (l&15);
            W2ap[(size_t)id2*8 + jj] = f2bf(W2a[(size_t)k*256 + n]);
        }
    } else if (id < 47616){
        int id2 = id - 45568;
        int kt = id2/512, rem = id2%512, nt = rem/64, l = rem%64;
#pragma unroll
        for (int jj = 0; jj < 8; ++jj){
            int k = kt*32 + ((l>>4)<<3) + jj, n = nt*16 + (l&15);
            Wsap[(size_t)id2*8 + jj] = f2bf(Wsa[(size_t)k*128 + n]);
        }
    } else if (id < 48128){
        int id2 = id - 47616;
        int kt = id2/256, rem = id2%256, nt = rem/64, l = rem%64;
#pragma unroll
        for (int jj = 0; jj < 8; ++jj){
            int k = kt*32 + ((l>>4)<<3) + jj, n = nt*16 + (l&15);
            Wvap[(size_t)id2*8 + jj] = f2bf(Wva[(size_t)k*64 + n]);
        }
    } else if (id < 50176){
        int id2 = id - 48128;
        int kt = id2/512, rem = id2%512, nt = rem/64, l = rem%64;
#pragma unroll
        for (int jj = 0; jj < 8; ++jj){
            int k = kt*32 + ((l>>4)<<3) + jj, n = nt*16 + (l&15);
            Wosp[(size_t)id2*8 + jj] = f2bf(Wos[(size_t)k*128 + n]);
        }
    } else if (id < 50688){
        int id2 = id - 50176;
        int kt = id2/256, rem = id2%256, nt = rem/64, l = rem%64;
#pragma unroll
        for (int jj = 0; jj < 8; ++jj){
            int k = kt*32 + ((l>>4)<<3) + jj, n = nt*16 + (l&15);
            Wovp[(size_t)id2*8 + jj] = f2bf(Wov[(size_t)k*64 + n]);
        }
    }
}

// ---------------------------------------------------------------- fused prep
#define PREP_B0 198                   // pack: 50688 ids
#define PREP_B1 (PREP_B0 + 2560)     // cvt: N_PROT*(16+24)
#define PREP_B2 (PREP_B1 + 1)        // ranges
#define PREP_B3 (PREP_B2 + 64)       // hfsB: 16384 ids
#define PREP_B4 (PREP_B3 + 512)      // tembB: 131072 ids
#define PREP_B5 (PREP_B4 + 32)       // fragsum: 8192 threads
#define PREP_NB (PREP_B5 + 64)       // ppos4: 16384 ids
__global__ __launch_bounds__(256) void k_prep(
    const float* __restrict__ W1, const float* __restrict__ W2,
    const float* __restrict__ Ws, const float* __restrict__ Wv,
    const float* __restrict__ W1a, const float* __restrict__ W2a,
    const float* __restrict__ Wsa, const float* __restrict__ Wva,
    const float* __restrict__ Wos, const float* __restrict__ Wov,
    const float* __restrict__ hps, const float* __restrict__ hpv,
    const float* __restrict__ hfsF, const float* __restrict__ tembF,
    const float* __restrict__ apos, const float* __restrict__ lpos,
    const float* __restrict__ ppos,
    const int* __restrict__ fid, const int* __restrict__ pbatch,
    short* __restrict__ W1p, short* __restrict__ W2p,
    short* __restrict__ Wsp, short* __restrict__ Wvp,
    short* __restrict__ W1cp,
    short* __restrict__ W1ap, short* __restrict__ W2ap,
    short* __restrict__ Wsap, short* __restrict__ Wvap,
    short* __restrict__ Wosp, short* __restrict__ Wovp,
    short* __restrict__ hpsB, short* __restrict__ hpvT,
    short* __restrict__ hfsB, short* __restrict__ tembB,
    float* __restrict__ ppos4,
    int* __restrict__ pstart,
    float* __restrict__ cnt, float* __restrict__ tsum, float* __restrict__ isum)
{
    const int b = blockIdx.x, t = threadIdx.x;
    if (b < PREP_B0){
        dev_pack(b*256 + t, W1, W2, Ws, Wv, W1a, W2a, Wsa, Wva, Wos, Wov,
                 W1p, W2p, Wsp, Wvp, W1cp, W1ap, W2ap, Wsap, Wvap, Wosp, Wovp);
    } else if (b < PREP_B1){
        int id = (b - PREP_B0)*256 + t;
        if (id < N_PROT*16){
            const float* s = hps + (size_t)id*8;
            float4 x0 = *(const float4*)(s);
            float4 x1 = *(const float4*)(s+4);
            unsigned* d = (unsigned*)(hpsB + (size_t)id*8);
            d[0] = f2bf2(x0.x, x0.y); d[1] = f2bf2(x0.z, x0.w);
            d[2] = f2bf2(x1.x, x1.y); d[3] = f2bf2(x1.z, x1.w);
        } else {
            int id2 = id - N_PROT*16;
            int j = id2 / 24, r = id2 % 24;
            short tmp[8];
#pragma unroll
            for (int u = 0; u < 8; ++u){
                int o = r*8 + u, c = o >> 6, v = o & 63;
                tmp[u] = f2bf(hpv[(size_t)j*192 + v*3 + c]);
            }
            *(bf16x8*)(hpvT + (size_t)j*192 + r*8) = *(bf16x8*)tmp;
        }
    } else if (b < PREP_B2){
        if (t <= 8){
            int lo = 0, hi = N_PROT;
            while (lo < hi){ int mid = (lo + hi) >> 1; if (pbatch[mid] < t) lo = mid + 1; else hi = mid; }
            pstart[t] = lo;
        }
    } else if (b < PREP_B3){
        int id = (b - PREP_B2)*256 + t;
        const float* s = hfsF + (size_t)id*8;
        float4 x0 = *(const float4*)(s);
        float4 x1 = *(const float4*)(s+4);
        unsigned* d = (unsigned*)(hfsB + (size_t)id*8);
        d[0] = f2bf2(x0.x, x0.y); d[1] = f2bf2(x0.z, x0.w);
        d[2] = f2bf2(x1.x, x1.y); d[3] = f2bf2(x1.z, x1.w);
    } else if (b < PREP_B4){
        int id = (b - PREP_B3)*256 + t;
        const float* s = tembF + (size_t)id*8;
        float4 x0 = *(const float4*)(s);
        float4 x1 = *(const float4*)(s+4);
        unsigned* d = (unsigned*)(tembB + (size_t)id*8);
        d[0] = f2bf2(x0.x, x0.y); d[1] = f2bf2(x0.z, x0.w);
        d[2] = f2bf2(x1.x, x1.y); d[3] = f2bf2(x1.z, x1.w);
    } else if (b < PREP_B5){
        int a = (b - PREP_B4)*256 + t;
        if (a < N_ATOM){
            int f = fid[a];
            atomicAdd(&cnt[f], 1.f);
            atomicAdd(&tsum[f*3+0], apos[a*3+0]);
            atomicAdd(&tsum[f*3+1], apos[a*3+1]);
            atomicAdd(&tsum[f*3+2], apos[a*3+2]);
            float x = lpos[a*3+0], y = lpos[a*3+1], z = lpos[a*3+2];
            float r2 = x*x + y*y + z*z;
            atomicAdd(&isum[f*9+0], r2 - x*x);
            atomicAdd(&isum[f*9+1], -(x*y));
            atomicAdd(&isum[f*9+2], -(x*z));
            atomicAdd(&isum[f*9+3], -(y*x));
            atomicAdd(&isum[f*9+4], r2 - y*y);
            atomicAdd(&isum[f*9+5], -(y*z));
            atomicAdd(&isum[f*9+6], -(z*x));
            atomicAdd(&isum[f*9+7], -(z*y));
            atomicAdd(&isum[f*9+8], r2 - z*z);
        }
    } else {
        int j = (b - PREP_B5)*256 + t;
        if (j < N_PROT){
            float px = ppos[j*3+0], py = ppos[j*3+1], pz = ppos[j*3+2];
            float p2 = px*px + py*py + pz*pz;
            *(float4*)(ppos4 + (size_t)j*4) = make_float4(px, py, pz, p2);
        }
    }
}

// ---------------------------------------------------------------- KNN: single-level linear-d2 radix select (exact top-32)
// register-slim: only kb[12] kept live; j and bin recomputed from (q,t) / kb.
__global__ __launch_bounds__(256) void k_knn(const float* __restrict__ apos,
                                             const float* __restrict__ ppos4,
                                             const int* __restrict__ abatch,
                                             const int* __restrict__ pstart,
                                             int* __restrict__ src_out){
    __shared__ int h1[256];
    __shared__ int s_info[4];
    __shared__ int s_nsel;
    __shared__ int s_nbound;
    __shared__ unsigned long long s_bound[512];

    const int i = blockIdx.x, t = threadIdx.x;
    const int lane = t & 63;
    const int b = abatch[i];
    const int p0 = pstart[b], p1 = pstart[b+1];
    const float ax = apos[i*3+0], ay = apos[i*3+1], az = apos[i*3+2];
    const float a2 = ax*ax + ay*ay + az*az;
    const float BINSCALE = 256.0f / 9.0f;
    const float4* pp4 = (const float4*)ppos4;

    unsigned kb[12];
#pragma unroll
    for (int q = 0; q < 12; ++q){
        int j = p0 + q*256 + t;
        unsigned kk = 0xFFFFFFFFu;
        if (j < p1){
            float4 pp = pp4[j];
            float dt = ax*pp.x + ay*pp.y + az*pp.z;
            float d2 = fmaxf((a2 + pp.w) - 2.0f*dt, 0.f);
            if (d2 <= 9.0f) kk = __float_as_uint(d2);
        }
        kb[q] = kk;
    }
    h1[t] = 0;
    if (t == 0){ s_nsel = 0; s_nbound = 0; }
    __syncthreads();
#pragma unroll
    for (int q = 0; q < 12; ++q){
        if (kb[q] != 0xFFFFFFFFu){
            int bin = (int)(__uint_as_float(kb[q]) * BINSCALE);
            if (bin > 255) bin = 255;
            atomicAdd(&h1[bin], 1);
        }
    }
    __syncthreads();
    if (t < 64){
        int base = t*4;
        int a0 = h1[base], a1 = h1[base+1], a2i = h1[base+2], a3 = h1[base+3];
        int lsum = a0 + a1 + a2i + a3;
        int sc = lsum;
#pragma unroll
        for (int off = 1; off < 64; off <<= 1){
            int v = __shfl_up(sc, off);
            if (lane >= off) sc += v;
        }
        int ex = sc - lsum;
        h1[base]   = ex + a0;
        h1[base+1] = ex + a0 + a1;
        h1[base+2] = ex + a0 + a1 + a2i;
        h1[base+3] = sc;
        if (t == 63) s_info[3] = sc;
    }
    __syncthreads();
    const int total = s_info[3];
    const int kth = (total < KNN) ? total : KNN;
    if (kth > 0){
        int cum  = h1[t];
        int prev = (t == 0) ? 0 : h1[t-1];
        if (cum >= kth && prev < kth){ s_info[0] = t; }
    }
    __syncthreads();
    const int B = s_info[0];
    if (kth > 0){
#pragma unroll
        for (int q = 0; q < 12; ++q){
            unsigned kk = kb[q];
            if (kk == 0xFFFFFFFFu) continue;
            int bin = (int)(__uint_as_float(kk) * BINSCALE);
            if (bin > 255) bin = 255;
            int j = p0 + q*256 + t;
            if (bin < B){
                int pos = atomicAdd(&s_nsel, 1);
                src_out[i*KNN + pos] = j;
            } else if (bin == B){
                int bi = atomicAdd(&s_nbound, 1);
                if (bi < 512) s_bound[bi] = ((unsigned long long)kk << 32) | (unsigned)j;
            }
        }
    }
    __syncthreads();
    const int base_n = s_nsel;
    const int R = kth - base_n;
    if (t < 64 && R > 0){
        int L = s_nbound; if (L > 512) L = 512;
        for (int r = 0; r < R; ++r){
            unsigned long long m = ~0ull;
            for (int idx = lane; idx < L; idx += 64) m = ullmin2(m, s_bound[idx]);
#pragma unroll
            for (int off = 32; off >= 1; off >>= 1)
                m = ullmin2(m, (unsigned long long)__shfl_xor((unsigned long long)m, off));
            if (lane == 0) src_out[i*KNN + base_n + r] = (int)(unsigned)(m & 0xFFFFFFFFull);
            for (int idx = lane; idx < L; idx += 64)
                if (s_bound[idx] == m) s_bound[idx] = ~0ull;
        }
    }
    if (t < KNN && t >= kth) src_out[i*KNN + t] = -1;
}

// ---------------------------------------------------------------- CSR prefix + frag centers (merged, 1 block x 1024)
__global__ __launch_bounds__(1024) void k_csr_prefix(const float* __restrict__ cnt,
                                                     const float* __restrict__ tsum,
                                                     const float* __restrict__ isum,
                                                     int* __restrict__ csr_off,
                                                     int* __restrict__ csr_cur,
                                                     float* __restrict__ tfrag,
                                                     float* __restrict__ ifin){
    __shared__ int s[1024];
    int t = threadIdx.x;
    float cn_raw = cnt[t];
    int v = (int)cn_raw;
    s[t] = v;
    {
        float cn = fmaxf(cn_raw, 1.f);
        tfrag[t*3+0] = tsum[t*3+0] / cn;
        tfrag[t*3+1] = tsum[t*3+1] / cn;
        tfrag[t*3+2] = tsum[t*3+2] / cn;
        float tr  = isum[t*9+0] + isum[t*9+4] + isum[t*9+8];
        float add = 1e-4f * fmaxf(tr, 1.f);
#pragma unroll
        for (int q = 0; q < 9; ++q){
            float vv = isum[t*9+q];
            if (q == 0 || q == 4 || q == 8) vv += add;
            ifin[t*9+q] = vv;
        }
    }
    __syncthreads();
    for (int off = 1; off < 1024; off <<= 1){
        int x = (t >= off) ? s[t-off] : 0;
        __syncthreads();
        s[t] += x;
        __syncthreads();
    }
    int incl = s[t];
    int excl = incl - v;
    csr_off[t] = excl;
    csr_cur[t] = excl;
    if (t == 1023) csr_off[1024] = incl;
}

__global__ void k_csr_scatter(const int* __restrict__ fid, int* __restrict__ csr_cur,
                              int* __restrict__ csr_atom){
    int a = blockIdx.x*256 + threadIdx.x;
    if (a >= N_ATOM) return;
    int f = fid[a];
    int pos = atomicAdd(&csr_cur[f], 1);
    csr_atom[pos] = a;
}

// ---------------------------------------------------------------- common[a][n] = b1[n] + [has|temb]_a . W1[144:400]
__global__ __launch_bounds__(256) void k_ctx(const float* __restrict__ has_,
                                             const float* __restrict__ temb,
                                             const short* __restrict__ W1cp,
                                             const float* __restrict__ b1,
                                             float* __restrict__ common){
    __shared__ __align__(16) char s_a[64*512];
    const int t = threadIdx.x, l = t & 63, w = t >> 6, g = l >> 4;
    const int a0 = blockIdx.x * 64;
    {
        int r = t & 63, seg = t >> 6;
        const float* srcp = (seg < 2) ? (has_ + (size_t)(a0 + r)*128 + seg*64)
                                      : (temb + (size_t)(a0 + r)*128 + (seg - 2)*64);
#pragma unroll
        for (int q = 0; q < 16; ++q){
            float4 x = *(const float4*)(srcp + q*4);
            int col = seg*64 + q*4;
            int off = (r*512 + col*2) ^ ((r & 7) << 4);
            *(unsigned*)(s_a + off)     = f2bf2(x.x, x.y);
            *(unsigned*)(s_a + off + 4) = f2bf2(x.z, x.w);
        }
    }
    __syncthreads();
    f32x4 acc[4][4];
#pragma unroll
    for (int mt = 0; mt < 4; ++mt)
#pragma unroll
        for (int nt = 0; nt < 4; ++nt) acc[mt][nt] = (f32x4){0.f,0.f,0.f,0.f};
    for (int ks = 0; ks < 8; ++ks){
        bf16x8 afr[4];
#pragma unroll
        for (int mt = 0; mt < 4; ++mt){
            int row = mt*16 + (l & 15);
            int off = (row*512 + ks*64 + g*16) ^ ((row & 7) << 4);
            afr[mt] = *(const bf16x8*)(s_a + off);
        }
#pragma unroll
        for (int nt = 0; nt < 4; ++nt){
            bf16x8 b = *(const bf16x8*)(W1cp + ((size_t)((ks*16 + (w*4 + nt))*64 + l))*8);
#pragma unroll
            for (int mt = 0; mt < 4; ++mt)
                acc[mt][nt] = __builtin_amdgcn_mfma_f32_16x16x32_bf16(afr[mt], b, acc[mt][nt], 0, 0, 0);
        }
    }
#pragma unroll
    for (int nt = 0; nt < 4; ++nt){
        int col = w*64 + nt*16 + (l & 15);
        float bb = b1[col];
#pragma unroll
        for (int mt = 0; mt < 4; ++mt)
#pragma unroll
            for (int r = 0; r < 4; ++r){
                int row = mt*16 + g*4 + r;
                common[(size_t)(a0 + row)*256 + col] = acc[mt][nt][r] + bb;
            }
    }
}

// ---------------------------------------------------------------- residue->atom conv (512 thr = 8 waves = 1 atom)
#define ES_STR 336   // bytes per es row (160 bf16 + 8 pad)
__global__ __launch_bounds__(512, 2) void k_ra3(
    const float* __restrict__ apos, const float* __restrict__ ppos,
    const short* __restrict__ hpsB, const short* __restrict__ hpvT,
    const short* __restrict__ W1p, const short* __restrict__ W2p,
    const short* __restrict__ Wsp, const short* __restrict__ Wvp,
    const float* __restrict__ common, const float* __restrict__ b2,
    const int* __restrict__ src,
    short* __restrict__ msR, short* __restrict__ mvR)
{
    __shared__ __align__(16) char s_es[32*ES_STR];
    __shared__ __align__(16) char s_h1[32*512];
    __shared__ __align__(16) char s_hpv[3*4096];
    __shared__ float s_unit[32][3];

    const int t = threadIdx.x;
    const int i = blockIdx.x;
    const int l = t & 63, w = t >> 6, g = l >> 4, r0 = l & 15;
    const int xm = (r0 & 7) << 4;
    float* s_mvA = (float*)s_es;
    float* s_mvB = s_mvA + 192;

    {
        const int e = t >> 4, sub = t & 15;
        const int j = src[i*KNN + e];
        float dx = 0.f, dy = 0.f, dz = 0.f, dist = 0.f;
        if (j >= 0){
            dx = apos[i*3+0] - ppos[j*3+0];
            dy = apos[i*3+1] - ppos[j*3+1];
            dz = apos[i*3+2] - ppos[j*3+2];
            dist = sqrtf(dx*dx + dy*dy + dz*dz);
        }
        if (sub == 0){
            float inv = 1.f / (dist + 1e-8f);
            s_unit[e][0] = dx*inv; s_unit[e][1] = dy*inv; s_unit[e][2] = dz*inv;
        }
        if (sub < 2){
            const float gamma = 16.0f / 6.0f;
#pragma unroll
            for (int q = 0; q < 4; ++q){
                int kk = sub*8 + q*2;
                float mu0  = 0.4f * (float)kk;
                float mu1  = 0.4f * (float)(kk+1);
                float a0 = gamma * (dist - mu0);
                float a1 = gamma * (dist - mu1);
                float e0 = (j >= 0) ? __expf(-(a0*a0)) : 0.f;
                float e1 = (j >= 0) ? __expf(-(a1*a1)) : 0.f;
                *(unsigned*)(s_es + e*ES_STR + kk*2) = f2bf2(e0, e1);
            }
        }
        if (sub < 8) *(int*)(s_es + e*ES_STR + 288 + sub*4) = 0;
        const bf16x8 zv = (bf16x8){0,0,0,0,0,0,0,0};
        {
            bf16x8 hc = (j >= 0) ? *(const bf16x8*)(hpsB + (size_t)j*128 + sub*8) : zv;
            *(bf16x8*)(s_es + e*ES_STR + 32 + sub*16) = hc;
        }
        const int em = (e & 7) << 4;
        {
            bf16x8 c0 = (j >= 0) ? *(const bf16x8*)(hpvT + (size_t)j*192 + sub*8) : zv;
            *(bf16x8*)(s_hpv + (sub>>3)*4096 + e*128 + (((sub&7)<<4) ^ em)) = c0;
            if (sub < 8){
                bf16x8 c1 = (j >= 0) ? *(const bf16x8*)(hpvT + (size_t)j*192 + (16+sub)*8) : zv;
                *(bf16x8*)(s_hpv + 2*4096 + e*128 + ((sub<<4) ^ em)) = c1;
            }
        }
    }
    __syncthreads();

    f32x4 acc1[2][2];
#pragma unroll
    for (int mt = 0; mt < 2; ++mt)
#pragma unroll
        for (int nt = 0; nt < 2; ++nt) acc1[mt][nt] = (f32x4){0.f,0.f,0.f,0.f};
    for (int ks = 0; ks < 5; ++ks){
        bf16x8 a0 = *(const bf16x8*)(s_es + r0*ES_STR + ks*64 + g*16);
        bf16x8 a1 = *(const bf16x8*)(s_es + (16 + r0)*ES_STR + ks*64 + g*16);
#pragma unroll
        for (int nt = 0; nt < 2; ++nt){
            bf16x8 b = *(const bf16x8*)(W1p + ((size_t)((ks*16 + (w*2 + nt))*64 + l))*8);
            acc1[0][nt] = __builtin_amdgcn_mfma_f32_16x16x32_bf16(a0, b, acc1[0][nt], 0, 0, 0);
            acc1[1][nt] = __builtin_amdgcn_mfma_f32_16x16x32_bf16(a1, b, acc1[1][nt], 0, 0, 0);
        }
    }

#pragma unroll
    for (int nt = 0; nt < 2; ++nt){
        int col = w*32 + nt*16 + r0;
        float cm = common[(size_t)i*256 + col];
#pragma unroll
        for (int mt = 0; mt < 2; ++mt)
#pragma unroll
            for (int r = 0; r < 4; ++r){
                float v = silu_f(acc1[mt][nt][r] + cm);
                int row = mt*16 + g*4 + r;
                int off = (row*512 + col*2) ^ ((row & 7) << 4);
                *(short*)(s_h1 + off) = f2bf(v);
            }
    }

    f32x4 accxs[2][2];
#pragma unroll
    for (int mt = 0; mt < 2; ++mt)
#pragma unroll
        for (int nt = 0; nt < 2; ++nt) accxs[mt][nt] = (f32x4){0.f,0.f,0.f,0.f};
    if (w < 4){
        for (int ks = 0; ks < 4; ++ks){
            bf16x8 a0 = *(const bf16x8*)(s_es + r0*ES_STR + 32 + ks*64 + g*16);
            bf16x8 a1 = *(const bf16x8*)(s_es + (16 + r0)*ES_STR + 32 + ks*64 + g*16);
#pragma unroll
            for (int nt = 0; nt < 2; ++nt){
                bf16x8 b = *(const bf16x8*)(Wsp + ((size_t)((ks*8 + (w*2 + nt))*64 + l))*8);
                accxs[0][nt] = __builtin_amdgcn_mfma_f32_16x16x32_bf16(a0, b, accxs[0][nt], 0, 0, 0);
                accxs[1][nt] = __builtin_amdgcn_mfma_f32_16x16x32_bf16(a1, b, accxs[1][nt], 0, 0, 0);
            }
        }
    }
    __syncthreads();

    f32x4 accw[2][2];
#pragma unroll
    for (int mt = 0; mt < 2; ++mt)
#pragma unroll
        for (int nt = 0; nt < 2; ++nt) accw[mt][nt] = (f32x4){0.f,0.f,0.f,0.f};
    for (int ks = 0; ks < 8; ++ks){
        int off0 = (r0*512 + ks*64 + g*16) ^ xm;
        bf16x8 a0 = *(const bf16x8*)(s_h1 + off0);
        bf16x8 a1 = *(const bf16x8*)(s_h1 + off0 + 8192);
#pragma unroll
        for (int nt = 0; nt < 2; ++nt){
            bf16x8 b = *(const bf16x8*)(W2p + ((size_t)((ks*16 + (w*2 + nt))*64 + l))*8);
            accw[0][nt] = __builtin_amdgcn_mfma_f32_16x16x32_bf16(a0, b, accw[0][nt], 0, 0, 0);
            accw[1][nt] = __builtin_amdgcn_mfma_f32_16x16x32_bf16(a1, b, accw[1][nt], 0, 0, 0);
        }
    }
    float b2v[2];
#pragma unroll
    for (int nt = 0; nt < 2; ++nt) b2v[nt] = b2[w*32 + nt*16 + r0];

    if (w < 4){
#pragma unroll
        for (int nt = 0; nt < 2; ++nt){
            float p = 0.f;
#pragma unroll
            for (int mt = 0; mt < 2; ++mt)
#pragma unroll
                for (int r = 0; r < 4; ++r)
                    p = fmaf(accw[mt][nt][r] + b2v[nt], accxs[mt][nt][r], p);
            p += __shfl_xor(p, 16);
            p += __shfl_xor(p, 32);
            if (l < 16) msR[(size_t)i*128 + w*32 + nt*16 + r0] = f2bf(p);
        }
    } else if (w < 6){
        bf16x8 bv[2][2];
#pragma unroll
        for (int ks = 0; ks < 2; ++ks)
#pragma unroll
            for (int nt = 0; nt < 2; ++nt)
                bv[ks][nt] = *(const bf16x8*)(Wvp + ((size_t)((ks*4 + (w-4)*2 + nt)*64 + l))*8);
#pragma unroll
        for (int c = 0; c < 3; ++c){
            f32x4 accxv[2][2];
#pragma unroll
            for (int mt = 0; mt < 2; ++mt)
#pragma unroll
                for (int nt = 0; nt < 2; ++nt) accxv[mt][nt] = (f32x4){0.f,0.f,0.f,0.f};
#pragma unroll
            for (int ks = 0; ks < 2; ++ks){
                int off0 = c*4096 + r0*128 + ((ks*64 + g*16) ^ xm);
                bf16x8 a0 = *(const bf16x8*)(s_hpv + off0);
                bf16x8 a1 = *(const bf16x8*)(s_hpv + off0 + 2048);
#pragma unroll
                for (int nt = 0; nt < 2; ++nt){
                    accxv[0][nt] = __builtin_amdgcn_mfma_f32_16x16x32_bf16(a0, bv[ks][nt], accxv[0][nt], 0, 0, 0);
                    accxv[1][nt] = __builtin_amdgcn_mfma_f32_16x16x32_bf16(a1, bv[ks][nt], accxv[1][nt], 0, 0, 0);
                }
            }
#pragma unroll
            for (int nt = 0; nt < 2; ++nt){
                float p = 0.f;
#pragma unroll
                for (int mt = 0; mt < 2; ++mt)
#pragma unroll
                    for (int r = 0; r < 4; ++r)
                        p = fmaf(accw[mt][nt][r] + b2v[nt], accxv[mt][nt][r], p);
                p += __shfl_xor(p, 16);
                p += __shfl_xor(p, 32);
                if (l < 16) s_mvA[c*64 + (w-4)*32 + nt*16 + r0] = p;
            }
        }
    } else {
        float uu[8][3];
#pragma unroll
        for (int mt = 0; mt < 2; ++mt)
#pragma unroll
            for (int r = 0; r < 4; ++r){
                int e = mt*16 + g*4 + r;
#pragma unroll
                for (int c = 0; c < 3; ++c) uu[mt*4+r][c] = s_unit[e][c];
            }
#pragma unroll
        for (int c = 0; c < 3; ++c)
#pragma unroll
            for (int nt = 0; nt < 2; ++nt){
                float p = 0.f;
#pragma unroll
                for (int mt = 0; mt < 2; ++mt)
#pragma unroll
                    for (int r = 0; r < 4; ++r)
                        p = fmaf(accw[mt][nt][r] + b2v[nt], uu[mt*4+r][c], p);
                p += __shfl_xor(p, 16);
                p += __shfl_xor(p, 32);
                if (l < 16) s_mvB[c*64 + (w-6)*32 + nt*16 + r0] = p;
            }
    }
    __syncthreads();

    if (t < 192){
        int wi = t & 63, cc = t >> 6;
        float v = s_mvA[cc*64 + wi] + s_mvB[cc*64 + wi];
        mvR[((size_t)i*3 + cc)*64 + wi] = f2bf(v);
    }
}

// ---------------------------------------------------------------- batched output transforms (MFMA) + bf16 dual-write
__global__ __launch_bounds__(256) void k_ra_out(
    const short* __restrict__ msR, const short* __restrict__ mvR,
    const short* __restrict__ Wosp, const short* __restrict__ Wovp,
    const float* __restrict__ has_, const float* __restrict__ hav,
    float* __restrict__ out,
    short* __restrict__ haB, short* __restrict__ havT)
{
    const int t = threadIdx.x, l = t & 63, w = t >> 6, g = l >> 4, r0 = l & 15;
    const int a0 = blockIdx.x * 32;

    f32x4 acc[2][2];
#pragma unroll
    for (int mt = 0; mt < 2; ++mt)
#pragma unroll
        for (int nt = 0; nt < 2; ++nt) acc[mt][nt] = (f32x4){0.f,0.f,0.f,0.f};
    for (int ks = 0; ks < 4; ++ks){
        bf16x8 af0 = *(const bf16x8*)(msR + ((size_t)(a0 + r0)*128 + ks*32 + g*8));
        bf16x8 af1 = *(const bf16x8*)(msR + ((size_t)(a0 + 16 + r0)*128 + ks*32 + g*8));
#pragma unroll
        for (int nt = 0; nt < 2; ++nt){
            bf16x8 b = *(const bf16x8*)(Wosp + ((size_t)((ks*8 + (w*2 + nt))*64 + l))*8);
            acc[0][nt] = __builtin_amdgcn_mfma_f32_16x16x32_bf16(af0, b, acc[0][nt], 0, 0, 0);
            acc[1][nt] = __builtin_amdgcn_mfma_f32_16x16x32_bf16(af1, b, acc[1][nt], 0, 0, 0);
        }
    }
#pragma unroll
    for (int nt = 0; nt < 2; ++nt){
        int col = w*32 + nt*16 + r0;
#pragma unroll
        for (int mt = 0; mt < 2; ++mt)
#pragma unroll
            for (int r = 0; r < 4; ++r){
                int a = a0 + mt*16 + g*4 + r;
                float val = has_[(size_t)a*128 + col] + silu_f(acc[mt][nt][r]);
                out[(size_t)a*OUTC + col] = val;
                haB[(size_t)a*128 + col] = f2bf(val);
            }
    }

    f32x4 accv[6];
#pragma unroll
    for (int mt = 0; mt < 6; ++mt) accv[mt] = (f32x4){0.f,0.f,0.f,0.f};
    for (int ks = 0; ks < 2; ++ks){
        bf16x8 b = *(const bf16x8*)(Wovp + ((size_t)((ks*4 + w)*64 + l))*8);
#pragma unroll
        for (int mt = 0; mt < 6; ++mt){
            bf16x8 af = *(const bf16x8*)(mvR + ((size_t)(a0*3 + mt*16 + r0)*64 + ks*32 + g*8));
            accv[mt] = __builtin_amdgcn_mfma_f32_16x16x32_bf16(af, b, accv[mt], 0, 0, 0);
        }
    }
    const int wi = w*16 + r0;
#pragma unroll
    for (int mt = 0; mt < 6; ++mt)
#pragma unroll
        for (int r = 0; r < 4; ++r){
            int R = mt*16 + g*4 + r;
            int a = a0 + R/3, c = R - (R/3)*3;
            float val = hav[(size_t)a*192 + wi*3 + c] + accv[mt][r];
            out[(size_t)a*OUTC + 128 + wi*3 + c] = val;
            havT[(size_t)a*192 + c*64 + wi] = f2bf(val);
        }
}

// ---------------------------------------------------------------- atom->frag conv, MFMA (1 block = 16 atoms, 2 blk/CU)
#define AES_STR 848  // bytes per es row (416 bf16 + 8 pad)
__global__ __launch_bounds__(256, 2) void k_af2(
    const float* __restrict__ apos, const float* __restrict__ tfrag,
    const short* __restrict__ haB, const short* __restrict__ hfsB,
    const short* __restrict__ tembB, const short* __restrict__ havT,
    const short* __restrict__ W1p, const float* __restrict__ b1,
    const short* __restrict__ W2p, const float* __restrict__ b2,
    const short* __restrict__ Wsp, const short* __restrict__ Wvp,
    const int* __restrict__ fragid,
    short* __restrict__ msA, short* __restrict__ mvA)
{
    __shared__ __align__(16) char s_es[16*AES_STR];
    __shared__ __align__(16) char s_h1[16*512];
    __shared__ __align__(16) char s_pv[3*2048];
    __shared__ float s_unit[16][3];
    float* s_upr = (float*)s_es;

    const int t = threadIdx.x, a0 = blockIdx.x*16;
    const int l = t & 63, w = t >> 6, g = l >> 4, r0 = l & 15;
    const int xm = (r0 & 7) << 4;

    {
        const int e = t >> 4, sub = t & 15;
        const int a = a0 + e;
        const int f = fragid[a];
        float rx = apos[a*3+0] - tfrag[f*3+0];
        float ry = apos[a*3+1] - tfrag[f*3+1];
        float rz = apos[a*3+2] - tfrag[f*3+2];
        float dist = sqrtf(rx*rx + ry*ry + rz*rz);
        if (sub == 0){
            float inv = 1.f / (dist + 1e-8f);
            s_unit[e][0] = rx*inv; s_unit[e][1] = ry*inv; s_unit[e][2] = rz*inv;
        }
        if (sub < 2){
            const float gamma = 16.0f / 6.0f;
#pragma unroll
            for (int q = 0; q < 4; ++q){
                int kk = sub*8 + q*2;
                float mu0  = 0.4f * (float)kk;
                float mu1  = 0.4f * (float)(kk+1);
                float a0f = gamma * (dist - mu0);
                float a1f = gamma * (dist - mu1);
                *(unsigned*)(s_es + e*AES_STR + kk*2) = f2bf2(__expf(-(a0f*a0f)), __expf(-(a1f*a1f)));
            }
        }
        *(bf16x8*)(s_es + e*AES_STR + 32  + sub*16) = *(const bf16x8*)(haB  + (size_t)a*128 + sub*8);
        *(bf16x8*)(s_es + e*AES_STR + 288 + sub*16) = *(const bf16x8*)(hfsB + (size_t)f*128 + sub*8);
        *(bf16x8*)(s_es + e*AES_STR + 544 + sub*16) = *(const bf16x8*)(tembB + (size_t)a*128 + sub*8);
        *(short*)(s_es + e*AES_STR + 800 + sub*2) = 0;
        const int em = (e & 7) << 4;
        {
            bf16x8 c0 = *(const bf16x8*)(havT + (size_t)a*192 + sub*8);
            *(bf16x8*)(s_pv + (sub>>3)*2048 + e*128 + (((sub&7)<<4) ^ em)) = c0;
            if (sub < 8){
                bf16x8 c1 = *(const bf16x8*)(havT + (size_t)a*192 + (16+sub)*8);
                *(bf16x8*)(s_pv + 2*2048 + e*128 + ((sub<<4) ^ em)) = c1;
            }
        }
    }
    __syncthreads();

    f32x4 acc1[4];
#pragma unroll
    for (int nt = 0; nt < 4; ++nt) acc1[nt] = (f32x4){0.f,0.f,0.f,0.f};
    for (int ks = 0; ks < 13; ++ks){
        bf16x8 a0f = *(const bf16x8*)(s_es + r0*AES_STR + ks*64 + g*16);
#pragma unroll
        for (int nt = 0; nt < 4; ++nt){
            bf16x8 b = *(const bf16x8*)(W1p + ((size_t)((ks*16 + (w*4 + nt))*64 + l))*8);
            acc1[nt] = __builtin_amdgcn_mfma_f32_16x16x32_bf16(a0f, b, acc1[nt], 0, 0, 0);
        }
    }
#pragma unroll
    for (int nt = 0; nt < 4; ++nt){
        int col = w*64 + nt*16 + r0;
        float bb = b1[col];
#pragma unroll
        for (int r = 0; r < 4; ++r){
            float v = silu_f(acc1[nt][r] + bb);
            int row = g*4 + r;
            int off = (row*512 + col*2) ^ ((row & 7) << 4);
            *(short*)(s_h1 + off) = f2bf(v);
        }
    }
    f32x4 accxs[4];
#pragma unroll
    for (int nt = 0; nt < 4; ++nt) accxs[nt] = (f32x4){0.f,0.f,0.f,0.f};
    if (w < 2){
        for (int ks = 0; ks < 4; ++ks){
            bf16x8 a0f = *(const bf16x8*)(s_es + r0*AES_STR + 32 + ks*64 + g*16);
#pragma unroll
            for (int nt = 0; nt < 4; ++nt){
                bf16x8 b = *(const bf16x8*)(Wsp + ((size_t)((ks*8 + (w*4 + nt))*64 + l))*8);
                accxs[nt] = __builtin_amdgcn_mfma_f32_16x16x32_bf16(a0f, b, accxs[nt], 0, 0, 0);
            }
        }
    }
    __syncthreads();

    f32x4 accw[4];
#pragma unroll
    for (int nt = 0; nt < 4; ++nt) accw[nt] = (f32x4){0.f,0.f,0.f,0.f};
    for (int ks = 0; ks < 8; ++ks){
        int off0 = (r0*512 + ks*64 + g*16) ^ xm;
        bf16x8 a0f = *(const bf16x8*)(s_h1 + off0);
#pragma unroll
        for (int nt = 0; nt < 4; ++nt){
            bf16x8 b = *(const bf16x8*)(W2p + ((size_t)((ks*16 + (w*4 + nt))*64 + l))*8);
            accw[nt] = __builtin_amdgcn_mfma_f32_16x16x32_bf16(a0f, b, accw[nt], 0, 0, 0);
        }
    }
    float b2v[4];
#pragma unroll
    for (int nt = 0; nt < 4; ++nt) b2v[nt] = b2[w*64 + nt*16 + r0];

    if (w == 3){
        float uu[4][3];
#pragma unroll
        for (int r = 0; r < 4; ++r){
            int e = g*4 + r;
#pragma unroll
            for (int c = 0; c < 3; ++c) uu[r][c] = s_unit[e][c];
        }
#pragma unroll
        for (int nt = 0; nt < 4; ++nt){
            int wi = nt*16 + r0;
#pragma unroll
            for (int r = 0; r < 4; ++r){
                int e = g*4 + r;
                float gate = accw[nt][r] + b2v[nt];
#pragma unroll
                for (int c = 0; c < 3; ++c)
                    s_upr[e*192 + wi*3 + c] = gate * uu[r][c];
            }
        }
    }
    __syncthreads();

    if (w < 2){
#pragma unroll
        for (int nt = 0; nt < 4; ++nt){
            int col = w*64 + nt*16 + r0;
#pragma unroll
            for (int r = 0; r < 4; ++r){
                int e = g*4 + r;
                float p = (accw[nt][r] + b2v[nt]) * accxs[nt][r];
                msA[(size_t)(a0 + e)*128 + col] = f2bf(p);
            }
        }
    } else if (w == 2){
        bf16x8 bv[2][4];
#pragma unroll
        for (int ks = 0; ks < 2; ++ks)
#pragma unroll
            for (int nt = 0; nt < 4; ++nt)
                bv[ks][nt] = *(const bf16x8*)(Wvp + ((size_t)((ks*4 + nt)*64 + l))*8);
#pragma unroll
        for (int c = 0; c < 3; ++c){
            f32x4 accxv[4];
#pragma unroll
            for (int nt = 0; nt < 4; ++nt) accxv[nt] = (f32x4){0.f,0.f,0.f,0.f};
#pragma unroll
            for (int ks = 0; ks < 2; ++ks){
                int off0 = c*2048 + r0*128 + ((ks*64 + g*16) ^ xm);
                bf16x8 a0f = *(const bf16x8*)(s_pv + off0);
#pragma unroll
                for (int nt = 0; nt < 4; ++nt)
                    accxv[nt] = __builtin_amdgcn_mfma_f32_16x16x32_bf16(a0f, bv[ks][nt], accxv[nt], 0, 0, 0);
            }
#pragma unroll
            for (int nt = 0; nt < 4; ++nt){
                int wi = nt*16 + r0;
#pragma unroll
                for (int r = 0; r < 4; ++r){
                    int e = g*4 + r;
                    float p = (accw[nt][r] + b2v[nt]) * accxv[nt][r]
                            + s_upr[e*192 + wi*3 + c];
                    mvA[(size_t)(a0 + e)*192 + wi*3 + c] = f2bf(p);
                }
            }
        }
    }
}

// ---------------------------------------------------------------- frag update (CSR gather + transform + direct scatter)
__global__ __launch_bounds__(256) void k_fragupd(
    const int* __restrict__ csr_off, const int* __restrict__ csr_atom,
    const short* __restrict__ msA, const short* __restrict__ mvA,
    const float* __restrict__ hfs_in, const float* __restrict__ hfv_in,
    const float* __restrict__ Wfs, const float* __restrict__ Wfv,
    const float* __restrict__ ifin,
    float* __restrict__ out)
{
    __shared__ __align__(16) float s_fs[128];
    __shared__ __align__(16) float s_fv[192];
    const int f = blockIdx.x, t = threadIdx.x;
    const int n0 = csr_off[f], n1 = csr_off[f+1];
    if (t < 128){
        float s = 0.f;
        for (int n = n0; n < n1; ++n){
            int a = csr_atom[n];
            s += bf2f(msA[(size_t)a*128 + t]);
        }
        s_fs[t] = s;
    }
    if (t >= 64){
        int idx = t - 64;
        float s = 0.f;
        for (int n = n0; n < n1; ++n){
            int a = csr_atom[n];
            s += bf2f(mvA[(size_t)a*192 + idx]);
        }
        s_fv[(idx % 3)*64 + (idx / 3)] = s;
    }
    __syncthreads();
    if (t < 128){
        float o = 0.f;
        for (int k = 0; k < 128; k += 4){
            const float* wr = &Wfs[k*128 + t];
            float4 m4 = *(const float4*)&s_fs[k];
            o = fmaf(m4.x, wr[0],   o);
            o = fmaf(m4.y, wr[128], o);
            o = fmaf(m4.z, wr[256], o);
            o = fmaf(m4.w, wr[384], o);
        }
        float val = hfs_in[f*128 + t] + silu_f(o);
        for (int n = n0; n < n1; ++n)
            out[(size_t)csr_atom[n]*OUTC + 320 + t] = val;
    }
    if (t < 192){
        const int wi = t & 63, cc = t >> 6;
        float o = 0.f;
        for (int v = 0; v < 64; v += 4){
            const float* wr = &Wfv[v*64 + wi];
            float4 m4 = *(const float4*)&s_fv[cc*64 + v];
            o = fmaf(m4.x, wr[0],   o);
            o = fmaf(m4.y, wr[64],  o);
            o = fmaf(m4.z, wr[128], o);
            o = fmaf(m4.w, wr[192], o);
        }
        float val = hfv_in[f*192 + wi*3 + cc] + o;
        for (int n = n0; n < n1; ++n)
            out[(size_t)csr_atom[n]*OUTC + 448 + wi*3 + cc] = val;
    } else if (t < 201){
        int q = t - 192;
        float val = ifin[f*9 + q];
        for (int n = n0; n < n1; ++n)
            out[(size_t)csr_atom[n]*OUTC + 640 + q] = val;
    }
}

// ----------------------------------------------------------------
extern "C" void kernel_launch(void* const* d_in, const int* in_sizes, int n_in,
                              void* d_out, int out_size, void* d_ws, size_t ws_size,
                              hipStream_t stream)
{
    const float* atom_pos   = (const float*)d_in[0];
    const float* prot_pos   = (const float*)d_in[1];
    const float* local_pos  = (const float*)d_in[2];
    const float* h_atom_s   = (const float*)d_in[3];
    const float* h_atom_v   = (const float*)d_in[4];
    const float* h_prot_s   = (const float*)d_in[5];
    const float* h_prot_v   = (const float*)d_in[6];
    const float* h_frag_s   = (const float*)d_in[7];
    const float* h_frag_v   = (const float*)d_in[8];
    const float* t_emb      = (const float*)d_in[9];
    const float* W1_ra = (const float*)d_in[10]; const float* b1_ra = (const float*)d_in[11];
    const float* W2_ra = (const float*)d_in[12]; const float* b2_ra = (const float*)d_in[13];
    const float* Ws_ra = (const float*)d_in[14]; const float* Wv_ra = (const float*)d_in[15];
    const float* W1_af = (const float*)d_in[16]; const float* b1_af = (const float*)d_in[17];
    const float* W2_af = (const float*)d_in[18]; const float* b2_af = (const float*)d_in[19];
    const float* Ws_af = (const float*)d_in[20]; const float* Wv_af = (const float*)d_in[21];
    const float* Wo_s  = (const float*)d_in[22]; const float* Wo_v  = (const float*)d_in[23];
    const float* Wf_s  = (const float*)d_in[24]; const float* Wf_v  = (const float*)d_in[25];
    const int* fragment_id = (const int*)d_in[26];
    const int* atom_batch  = (const int*)d_in[27];
    const int* prot_batch  = (const int*)d_in[28];
    float* out = (float*)d_out;

    // ---- workspace layout ----
    float* cnt   = (float*)d_ws;                 // 1024   (zeroed)
    float* tsum  = cnt  + 1024;                  // 3072   (zeroed)
    float* isum  = tsum + 3072;                  // 9216   (zeroed)
    float* tfrag = isum + 9216;                  // 3072
    float* ifin  = tfrag + 3072;                 // 9216
    float* hfs   = ifin + 9216;                  // 131072 (unused, layout stability)
    float* hfv   = hfs  + 1024*128;              // 196608 (unused)
    int*   pstart   = (int*)(hfv + 1024*192);    // 16
    int*   src      = pstart + 16;               // 262144
    int*   csr_off  = src + N_ATOM*KNN;          // 1025
    int*   csr_cur  = csr_off + 1025;            // 1024
    int*   csr_atom = csr_cur + 1024;            // 8192
    uintptr_t pal = ((uintptr_t)(csr_atom + 8192) + 127) & ~(uintptr_t)127;
    float* common = (float*)pal;                 // 8192*256 f32 (8 MB)
    // aliases inside common (dead after k_ra3):
    short* msA  = (short*)common;                // 2 MB  (written k_af2)
    short* mvA  = msA + (size_t)8192*128;        // 3 MB  (written k_af2)
    short* havT = mvA + (size_t)8192*192;        // 3 MB  (written k_ra_out)
    short* W1p  = (short*)(common + (size_t)8192*256);
    short* W2p  = W1p  + 40960;
    short* Wsp  = W2p  + 65536;
    short* Wvp  = Wsp  + 16384;
    short* W1cp = Wvp  + 4096;
    short* W1ap = W1cp + 65536;
    short* W2ap = W1ap + 106496;
    short* Wsap = W2ap + 65536;
    short* Wvap = Wsap + 16384;
    short* Wosp = Wvap + 4096;
    short* Wovp = Wosp + 16384;
    short* msR  = Wovp + 4096;                   // 8192*128 bf16 (2 MB)
    short* mvR  = msR + (size_t)8192*128;        // 8192*192 bf16 (3 MB)
    short* hpsB = mvR + (size_t)8192*192;        // 16384*128 bf16 (4 MB)
    short* hpvT = hpsB + (size_t)N_PROT*128;     // 16384*192 bf16 (6 MB)
    short* haB  = hpvT + (size_t)N_PROT*192;     // 8192*128 bf16 (2 MB)
    short* hfsB = haB + (size_t)8192*128;        // 1024*128 bf16 (256 KB)
    short* tembB= hfsB + (size_t)1024*128;       // 8192*128 bf16 (2 MB)
    uintptr_t p4 = ((uintptr_t)(tembB + (size_t)8192*128) + 15) & ~(uintptr_t)15;
    float* ppos4 = (float*)p4;                   // 16384*4 f32 (256 KB)

    size_t zero_bytes = (size_t)(1024 + 3072 + 9216) * sizeof(float);
    hipMemsetAsync(cnt, 0, zero_bytes, stream);

    k_prep    <<<PREP_NB, 256, 0, stream>>>(W1_ra, W2_ra, Ws_ra, Wv_ra, W1_af, W2_af, Ws_af, Wv_af,
                                            Wo_s, Wo_v,
                                            h_prot_s, h_prot_v, h_frag_s, t_emb,
                                            atom_pos, local_pos, prot_pos,
                                            fragment_id, prot_batch,
                                            W1p, W2p, Wsp, Wvp, W1cp, W1ap, W2ap, Wsap, Wvap,
                                            Wosp, Wovp,
                                            hpsB, hpvT, hfsB, tembB, ppos4, pstart,
                                            cnt, tsum, isum);
    k_knn     <<<N_ATOM, 256, 0, stream>>>(atom_pos, ppos4, atom_batch, pstart, src);
    k_ctx     <<<N_ATOM/64, 256, 0, stream>>>(h_atom_s, t_emb, W1cp, b1_ra, common);
    k_csr_prefix<<<1, 1024, 0, stream>>>(cnt, tsum, isum, csr_off, csr_cur, tfrag, ifin);
    k_csr_scatter<<<N_ATOM/256, 256, 0, stream>>>(fragment_id, csr_cur, csr_atom);
    k_ra3     <<<N_ATOM, 512, 0, stream>>>(atom_pos, prot_pos, hpsB, hpvT,
                                           W1p, W2p, Wsp, Wvp, common, b2_ra,
                                           src, msR, mvR);
    k_ra_out  <<<N_ATOM/32, 256, 0, stream>>>(msR, mvR, Wosp, Wovp, h_atom_s, h_atom_v, out,
                                              haB, havT);
    k_af2     <<<N_ATOM/16, 256, 0, stream>>>(atom_pos, tfrag, haB, hfsB, tembB, havT,
                                              W1ap, b1_af, W2ap, b2_af, Wsap, Wvap,
                                              fragment_id, msA, mvA);
    k_fragupd <<<N_FRAG, 256, 0, stream>>>(csr_off, csr_atom, msA, mvA,
                                           h_frag_s, h_frag_v, Wf_s, Wf_v, ifin, out);
}